// Round 13
// baseline (554.424 us; speedup 1.0000x reference)
//
#include <hip/hip_runtime.h>
#include <hip/hip_bf16.h>

#define NN 16384
#define GG 2048
#define KNN 16
#define EE (NN*KNN)
#define NL 4

typedef _Float16 f16;
typedef _Float16 half8 __attribute__((ext_vector_type(8)));
typedef _Float16 half4 __attribute__((ext_vector_type(4)));
typedef float f32x4 __attribute__((ext_vector_type(4)));
typedef unsigned long long u64;

// gelu tanh-approx in sigmoid form: x*sigmoid(2y), y=a(x+b x^3)
__device__ __forceinline__ float gelu_tanh(float x) {
  float s = x*x;
  float u = __fmaf_rn(-0.0713548194f, s, -1.5957691216f);   // -2ab*s - 2a
  float p = __expf(x*u);
  return x * __builtin_amdgcn_rcpf(1.0f + p);
}

__device__ __forceinline__ int mbcnt64(u64 m) {
  return __builtin_amdgcn_mbcnt_hi((unsigned)(m >> 32),
         __builtin_amdgcn_mbcnt_lo((unsigned)m, 0));
}

// ---------------- kNN v6 (R12: ~55us; f32 scan chain + ballot bit-descend) ----------
__global__ __launch_bounds__(256) void knn_kernel(const float* __restrict__ pos,
    int* __restrict__ srci, float* __restrict__ dedge) {
  __shared__ u64 sel[4][16];            // per-wave survivor slots (512 B)
  int tid = threadIdx.x;
  int wv = tid >> 6;
  int node = blockIdx.x*4 + wv;
  int lane = tid & 63;
  int base = node & ~(GG-1);
  float qx = pos[(size_t)node*3+0], qy = pos[(size_t)node*3+1], qz = pos[(size_t)node*3+2];

  float d2s[32];
  float c0 = 3.4e38f, c1 = 3.4e38f, c2 = 3.4e38f, c3 = 3.4e38f;
  #pragma unroll
  for (int it = 0; it < 32; ++it) {
    int j = it*64 + lane;
    const float* pr = pos + (size_t)(base+j)*3;
    float dx = __fsub_rn(qx, pr[0]);
    float dy = __fsub_rn(qy, pr[1]);
    float dz = __fsub_rn(qz, pr[2]);
    float d2 = __fadd_rn(__fadd_rn(__fmul_rn(dx,dx), __fmul_rn(dy,dy)), __fmul_rn(dz,dz));
    d2s[it] = d2;
    float x = d2;
    float t0 = fminf(c0, x); x = fmaxf(c0, x); c0 = t0;
    float t1 = fminf(c1, x); x = fmaxf(c1, x); c1 = t1;
    float t2 = fminf(c2, x); x = fmaxf(c2, x); c2 = t2;
    c3 = fminf(c3, x);
  }
  unsigned T = 0;
  for (int b = 30; b >= 0; --b) {
    unsigned tb = T | (1u << b);
    float tf = __uint_as_float(tb);
    int cnt = __popcll(__ballot(c0 < tf)) + __popcll(__ballot(c1 < tf))
            + __popcll(__ballot(c2 < tf)) + __popcll(__ballot(c3 < tf));
    if (cnt < 16) T = tb;
  }
  float Tf = __uint_as_float(T);
  int cless;
  if (!__any(c3 <= Tf)) {
    cless = __popcll(__ballot(c0 < Tf)) + __popcll(__ballot(c1 < Tf))
          + __popcll(__ballot(c2 < Tf)) + __popcll(__ballot(c3 < Tf));
  } else {
    T = 0;
    for (int b = 30; b >= 0; --b) {
      unsigned tb = T | (1u << b);
      float tf = __uint_as_float(tb);
      int cnt = 0;
      #pragma unroll
      for (int q = 0; q < 32; ++q) cnt += __popcll(__ballot(d2s[q] < tf));
      if (cnt < 16) T = tb;
    }
    Tf = __uint_as_float(T);
    cless = 0;
    #pragma unroll
    for (int q = 0; q < 32; ++q) cless += __popcll(__ballot(d2s[q] < Tf));
  }
  int offb = 0;
  int tieq = 16 - cless;
  #pragma unroll
  for (int it = 0; it < 32; ++it) {
    u64 mless = __ballot(d2s[it] < Tf);
    u64 mtie  = __ballot(d2s[it] == Tf);
    bool store = (d2s[it] < Tf);
    int slot = offb + mbcnt64(mless);
    offb += (int)__popcll(mless);
    if (mtie != 0 && tieq > 0) {
      int tr = mbcnt64(mtie);
      if (d2s[it] == Tf && tr < tieq) { store = true; slot = offb + tr; }
      int take = (int)__popcll(mtie); take = take < tieq ? take : tieq;
      offb += take; tieq -= take;
    }
    if (store)
      sel[wv][slot] = ((u64)__float_as_uint(d2s[it]) << 32) | (unsigned)(it*64 + lane);
  }
  if (lane < KNN) {
    u64 e = sel[wv][lane];
    int rank = 0;
    #pragma unroll
    for (int k2 = 0; k2 < 16; ++k2) rank += (sel[wv][k2] < e) ? 1 : 0;
    int j = (int)(e & 0xffffffffu);
    float d2v = __uint_as_float((unsigned)(e >> 32));
    srci[node*KNN + rank] = base + j;
    dedge[node*KNN + rank] = sqrtf(__fadd_rn(d2v, 1e-12f));
  }
}

// ---------------- weight transpose + f16 convert (transposed [col][k] layouts) -------
__global__ __launch_bounds__(256) void prep_kernel(
    const float* __restrict__ Wb2, const float* __restrict__ Wk,
    const float* __restrict__ W1, const float* __restrict__ W2,
    f16* __restrict__ Wb2t, f16* __restrict__ Wkt,
    f16* __restrict__ W1t, f16* __restrict__ W2t) {
  int i = blockIdx.x*256 + threadIdx.x;
  if (i < 16384) {
    int c = i >> 7, k = i & 127;
    Wb2t[i] = (f16)Wb2[k*128 + c];
    return;
  }
  i -= 16384;
  if (i < 65536) {
    int l = i >> 14, r = i & 16383; int c = r >> 7, k = r & 127;
    Wkt[i] = (f16)Wk[l*16384 + k*128 + c];
    return;
  }
  i -= 65536;
  if (i < 262144) {
    int l = i >> 16, r = i & 65535; int c = r >> 7, k = r & 127;   // c<512,k<128
    W1t[i] = (f16)W1[l*65536 + k*512 + c];
    return;
  }
  i -= 262144;
  if (i < 262144) {
    int l = i >> 16, r = i & 65535; int c = r >> 9, k = r & 511;   // c<128,k<512
    W2t[i] = (f16)W2[l*65536 + k*128 + c];
  }
}

// ---------------- embed: h = x[N,65] @ We[65,128] (f32 VALU) -------------------------
__global__ __launch_bounds__(256) void embed_kernel(const float* __restrict__ x,
    const float* __restrict__ We, float* __restrict__ h) {
  int t = threadIdx.x;
  int n = blockIdx.x*8 + (t >> 5);
  int q = (t & 31) * 4;
  f32x4 acc = {0.f,0.f,0.f,0.f};
  const float* xr = x + n*65;
  for (int k = 0; k < 65; ++k) {
    float xv = xr[k];
    f32x4 wv = *(const f32x4*)(We + k*128 + q);
    acc += xv * wv;
  }
  *(f32x4*)(h + (size_t)n*128 + q) = acc;
}

// ---------------- edge basis v5: Wb2 staged in LDS -----------------------------------
__global__ __launch_bounds__(256) void basis_kernel(const float* __restrict__ dedge,
    const float* __restrict__ Wb1, const float* __restrict__ bb1,
    const f16* __restrict__ Wb2t, const float* __restrict__ bb2,
    f16* __restrict__ kernA) {
  __shared__ f16 Wb2s[128][136];  // 34.8KB, padded: B-frag ds_read_b128 2-way max
  __shared__ f16 kb[64][136];     // 17.4KB, rows w*16.. private per wave
  int t = threadIdx.x;
  #pragma unroll
  for (int it = 0; it < 8; ++it) {      // stage Wb2t (32KB) coalesced
    int idx = it*256 + t;
    int row = idx >> 4, k8 = (idx & 15) * 8;
    *(half8*)&Wb2s[row][k8] = *(const half8*)&Wb2t[row*128 + k8];
  }
  __syncthreads();
  int w = t >> 6, l = t & 63;
  int row4 = l >> 4, rlo = l & 15;
  #pragma unroll
  for (int tt = 0; tt < 2; ++tt) {
    size_t Tg = (size_t)blockIdx.x*8 + (size_t)w*2 + tt;
    float d = dedge[Tg*16 + rlo];
    float d2 = d*d, d3 = d2*d;
    half8 a[4];
    #pragma unroll
    for (int kc = 0; kc < 4; ++kc) {
      int k0 = kc*32 + row4*8;
      f32x4 w1a = *(const f32x4*)&Wb1[k0],     w1b = *(const f32x4*)&Wb1[k0+4];
      f32x4 w2a = *(const f32x4*)&Wb1[128+k0], w2b = *(const f32x4*)&Wb1[128+k0+4];
      f32x4 w3a = *(const f32x4*)&Wb1[256+k0], w3b = *(const f32x4*)&Wb1[256+k0+4];
      f32x4 bba = *(const f32x4*)&bb1[k0],     bbb = *(const f32x4*)&bb1[k0+4];
      #pragma unroll
      for (int j = 0; j < 4; ++j) {
        a[kc][j]   = (f16)gelu_tanh(d*w1a[j] + d2*w2a[j] + d3*w3a[j] + bba[j]);
        a[kc][4+j] = (f16)gelu_tanh(d*w1b[j] + d2*w2b[j] + d3*w3b[j] + bbb[j]);
      }
    }
    f32x4 acc[8];
    #pragma unroll
    for (int nt = 0; nt < 8; ++nt) {
      acc[nt] = (f32x4){0.f,0.f,0.f,0.f};
      #pragma unroll
      for (int kc = 0; kc < 4; ++kc) {
        half8 b = *(const half8*)&Wb2s[nt*16 + rlo][kc*32 + row4*8];
        acc[nt] = __builtin_amdgcn_mfma_f32_16x16x32_f16(a[kc], b, acc[nt], 0, 0, 0);
      }
    }
    #pragma unroll
    for (int nt = 0; nt < 8; ++nt) {
      float bias = bb2[nt*16 + rlo];
      #pragma unroll
      for (int j = 0; j < 4; ++j)
        kb[w*16 + row4*4 + j][nt*16 + rlo] = (f16)gelu_tanh(acc[nt][j] + bias);
    }
    #pragma unroll
    for (int kc = 0; kc < 4; ++kc) {
      half8 v = *(const half8*)&kb[w*16 + rlo][kc*32 + row4*8];
      *(half8*)&kernA[((Tg*4 + kc)*64 + l)*8] = v;
    }
  }
}

// ---------------- fused layer v5: XCD swizzle + hv double-buffer --------------------
// R12 counters: 62us, MFMA 7.7%/VALU 12%/HBM 15%/occ 20% -> latency-chained on the
// hv gathers (~300cyc exposed x8/wave) + L3-distance gathers. Fix 1: bijective XCD
// swizzle (1024 blocks = 8 XCDs x 128): same-graph blocks share an XCD -> hin slice
// (1MB) lives in that XCD's 4MB L2. Fix 2: hv prefetched one node ahead (PREH/COMPU
// split); VGPR capped at 128 via launch_bounds (129+ halves occupancy - R10 lesson).
#define LOADA(arr, mm) { \
  int node_ = n0 + w*4 + (mm); \
  _Pragma("unroll") \
  for (int kc = 0; kc < 4; ++kc) \
    arr[kc] = *(const half8*)&kernA[(((size_t)node_*4 + kc)*64 + l)*8]; }

#define PREH(hvv, mm) { \
  _Pragma("unroll") \
  for (int nt4 = 0; nt4 < 4; ++nt4) \
    _Pragma("unroll") \
    for (int j = 0; j < 4; ++j) \
      hvv[nt4][j] = hin[(size_t)sidxA[mm][j]*128 + (hh*4 + nt4)*16 + rlo]; }

#define COMPU(arr, hvv, mm) { \
  _Pragma("unroll") \
  for (int nt4 = 0; nt4 < 4; ++nt4) { \
    f32x4 acc = {0.f,0.f,0.f,0.f}; \
    _Pragma("unroll") \
    for (int kc = 0; kc < 4; ++kc) \
      acc = __builtin_amdgcn_mfma_f32_16x16x32_f16(arr[kc], bf[nt4][kc], acc, 0, 0, 0); \
    float p = 0.f; \
    _Pragma("unroll") \
    for (int j = 0; j < 4; ++j) p += acc[j] * hvv[nt4][j]; \
    p += __shfl_xor(p, 16, 64); \
    p += __shfl_xor(p, 32, 64); \
    if (l < 16) aggl[w*4 + (mm)][(hh*4 + nt4)*16 + l] = p; \
  } }

__global__ __launch_bounds__(256, 4) void layer_kernel(const f16* __restrict__ kernA,
    const f16* __restrict__ Wkt_l, const int* __restrict__ srci,
    const float* __restrict__ hin,
    const float* __restrict__ lng, const float* __restrict__ lnb,
    const f16* __restrict__ W1t_l, const float* __restrict__ b1_l,
    const f16* __restrict__ W2t_l, const float* __restrict__ b2_l,
    float* __restrict__ hout) {
  __shared__ float aggl[16][132];   // 8.4KB  conv output (wave-private rows)
  __shared__ f16 zl[16][136];       // 4.4KB  LN output
  __shared__ f16 y1[16][520];       // 16.6KB full y1
  int t = threadIdx.x;
  int w = t >> 6, l = t & 63;
  int row4 = l >> 4, rlo = l & 15;
  // XCD swizzle: physical block i runs on XCD i%8; logical graph g = 128 blocks
  // -> logical = (i%8)*128 + i/8 puts graph g wholly on XCD g. Bijective for 1024.
  int bid = (blockIdx.x & 7)*128 + (blockIdx.x >> 3);
  int n0 = bid * 16;

  int sidxA[4][4];
  #pragma unroll
  for (int m = 0; m < 4; ++m)
    #pragma unroll
    for (int j = 0; j < 4; ++j)
      sidxA[m][j] = srci[(n0 + w*4 + m)*16 + row4*4 + j];

  #pragma unroll
  for (int hh = 0; hh < 2; ++hh) {
    half8 bf[4][4];
    #pragma unroll
    for (int nt4 = 0; nt4 < 4; ++nt4)
      #pragma unroll
      for (int kc = 0; kc < 4; ++kc)
        bf[nt4][kc] = *(const half8*)&Wkt_l[((hh*4 + nt4)*16 + rlo)*128 + kc*32 + row4*8];
    half8 aA[4], aB[4];
    float vA[4][4], vB[4][4];
    LOADA(aA, 0) PREH(vA, 0)
    LOADA(aB, 1) PREH(vB, 1)
    COMPU(aA, vA, 0)
    LOADA(aA, 2) PREH(vA, 2)
    COMPU(aB, vB, 1)
    LOADA(aB, 3) PREH(vB, 3)
    COMPU(aA, vA, 2)
    COMPU(aB, vB, 3)
  }
  __syncthreads();
  {
    int row = w*4 + row4;
    int cb = rlo*8;
    f32x4 va = *(const f32x4*)&aggl[row][cb];
    f32x4 vb = *(const f32x4*)&aggl[row][cb+4];
    float s = va[0]+va[1]+va[2]+va[3] + vb[0]+vb[1]+vb[2]+vb[3];
    #pragma unroll
    for (int st = 1; st < 16; st <<= 1) s += __shfl_xor(s, st, 64);
    float mu = s * (1.f/128.f);
    f32x4 da = va - mu, db = vb - mu;
    float s2 = da[0]*da[0]+da[1]*da[1]+da[2]*da[2]+da[3]*da[3]
             + db[0]*db[0]+db[1]*db[1]+db[2]*db[2]+db[3]*db[3];
    #pragma unroll
    for (int st = 1; st < 16; st <<= 1) s2 += __shfl_xor(s2, st, 64);
    float inv = rsqrtf(s2*(1.f/128.f) + 1e-5f);
    f32x4 ga = *(const f32x4*)&lng[cb], gb = *(const f32x4*)&lng[cb+4];
    f32x4 ba = *(const f32x4*)&lnb[cb], bb = *(const f32x4*)&lnb[cb+4];
    f32x4 za = da*inv*ga + ba, zb = db*inv*gb + bb;
    half8 hz = { (f16)za[0],(f16)za[1],(f16)za[2],(f16)za[3],
                 (f16)zb[0],(f16)zb[1],(f16)zb[2],(f16)zb[3] };
    *(half8*)&zl[row][cb] = hz;
  }
  __syncthreads();
  half8 az[4];
  #pragma unroll
  for (int kc = 0; kc < 4; ++kc)
    az[kc] = *(const half8*)&zl[rlo][kc*32 + row4*8];
  #pragma unroll
  for (int ntl = 0; ntl < 8; ++ntl) {
    int nt = w*8 + ntl;
    int col = nt*16 + rlo;
    f32x4 acc = {0.f,0.f,0.f,0.f};
    #pragma unroll
    for (int kc = 0; kc < 4; ++kc) {
      half8 b = *(const half8*)&W1t_l[(size_t)col*128 + kc*32 + row4*8];
      acc = __builtin_amdgcn_mfma_f32_16x16x32_f16(az[kc], b, acc, 0, 0, 0);
    }
    float bias = b1_l[col];
    #pragma unroll
    for (int j = 0; j < 4; ++j)
      y1[row4*4 + j][col] = (f16)gelu_tanh(acc[j] + bias);
  }
  __syncthreads();
  half8 a2[16];
  #pragma unroll
  for (int kc2 = 0; kc2 < 16; ++kc2)
    a2[kc2] = *(const half8*)&y1[rlo][kc2*32 + row4*8];
  f32x4 acc2[2] = {{0.f,0.f,0.f,0.f},{0.f,0.f,0.f,0.f}};
  #pragma unroll
  for (int nt2 = 0; nt2 < 2; ++nt2) {
    int c = (w*2 + nt2)*16 + rlo;
    #pragma unroll
    for (int kc2 = 0; kc2 < 16; ++kc2) {
      half8 b = *(const half8*)&W2t_l[(size_t)c*512 + kc2*32 + row4*8];
      acc2[nt2] = __builtin_amdgcn_mfma_f32_16x16x32_f16(a2[kc2], b, acc2[nt2], 0, 0, 0);
    }
  }
  #pragma unroll
  for (int nt2 = 0; nt2 < 2; ++nt2) {
    int col = (w*2 + nt2)*16 + rlo;
    float bias = b2_l[col];
    #pragma unroll
    for (int j = 0; j < 4; ++j) {
      size_t n = (size_t)(n0 + w*4 + 0) ; // placeholder avoided; real below
    }
  }
  #pragma unroll
  for (int nt2 = 0; nt2 < 2; ++nt2) {
    int col = (w*2 + nt2)*16 + rlo;
    float bias = b2_l[col];
    #pragma unroll
    for (int j = 0; j < 4; ++j) {
      size_t n = (size_t)(n0 + row4*4 + j);
      hout[n*128 + col] = acc2[nt2][j] + bias + hin[n*128 + col];
    }
  }
}

// ---------------- readout ------------------------------------------------------------
__global__ __launch_bounds__(256) void readout_kernel(const float* __restrict__ h,
    const float* __restrict__ Wr, const float* __restrict__ br, float* __restrict__ out) {
  int n = blockIdx.x*256 + threadIdx.x;
  f32x4 acc = {0.f,0.f,0.f,0.f};
  #pragma unroll
  for (int cb = 0; cb < 32; ++cb) {
    f32x4 hv = *(const f32x4*)(h + (size_t)n*128 + cb*4);
    f32x4 wv = *(const f32x4*)(Wr + cb*4);
    acc += hv*wv;
  }
  out[n] = acc[0]+acc[1]+acc[2]+acc[3] + br[0];
}

extern "C" void kernel_launch(void* const* d_in, const int* in_sizes, int n_in,
                              void* d_out, int out_size, void* d_ws, size_t ws_size,
                              hipStream_t stream) {
  const float* x   = (const float*)d_in[0];
  const float* pos = (const float*)d_in[1];
  const float* We  = (const float*)d_in[3];
  const float* Wb1 = (const float*)d_in[4];
  const float* bb1 = (const float*)d_in[5];
  const float* Wb2 = (const float*)d_in[6];
  const float* bb2 = (const float*)d_in[7];
  const float* Wk  = (const float*)d_in[8];
  const float* lng = (const float*)d_in[9];
  const float* lnb = (const float*)d_in[10];
  const float* W1  = (const float*)d_in[11];
  const float* b1  = (const float*)d_in[12];
  const float* W2  = (const float*)d_in[13];
  const float* b2  = (const float*)d_in[14];
  const float* Wr  = (const float*)d_in[15];
  const float* br  = (const float*)d_in[16];
  float* out = (float*)d_out;

  char* p = (char*)d_ws;
  int*   srci  = (int*)p;     p += (size_t)EE*4;
  float* dedge = (float*)p;   p += (size_t)EE*4;
  f16*   kernA = (f16*)p;     p += (size_t)EE*128*2;
  float* hA    = (float*)p;   p += (size_t)NN*128*4;
  float* hB    = (float*)p;   p += (size_t)NN*128*4;
  f16* Wb2t    = (f16*)p;     p += (size_t)16384*2;
  f16* Wkt     = (f16*)p;     p += (size_t)65536*2;
  f16* W1t     = (f16*)p;     p += (size_t)262144*2;
  f16* W2t     = (f16*)p;     p += (size_t)262144*2;

  prep_kernel<<<2368, 256, 0, stream>>>(Wb2, Wk, W1, W2, Wb2t, Wkt, W1t, W2t);
  knn_kernel<<<NN/4, 256, 0, stream>>>(pos, srci, dedge);
  basis_kernel<<<2048, 256, 0, stream>>>(dedge, Wb1, bb1, Wb2t, bb2, kernA);
  embed_kernel<<<NN/8, 256, 0, stream>>>(x, We, hA);
  float* hin = hA;
  for (int lyr = 0; lyr < NL; ++lyr) {
    float* hout = (hin == hA) ? hB : hA;
    layer_kernel<<<NN/16, 256, 0, stream>>>(kernA, Wkt + lyr*16384, srci, hin,
        lng + lyr*128, lnb + lyr*128,
        W1t + (size_t)lyr*65536, b1 + lyr*512, W2t + (size_t)lyr*65536, b2 + lyr*128, hout);
    hin = hout;
  }
  readout_kernel<<<NN/256, 256, 0, stream>>>(hin, Wr, br, out);
}

// Round 14
// 357.779 us; speedup vs baseline: 1.5496x; 1.5496x over previous
//
#include <hip/hip_runtime.h>
#include <hip/hip_bf16.h>

#define NN 16384
#define GG 2048
#define KNN 16
#define EE (NN*KNN)
#define NL 4

typedef _Float16 f16;
typedef _Float16 half8 __attribute__((ext_vector_type(8)));
typedef _Float16 half4 __attribute__((ext_vector_type(4)));
typedef float f32x4 __attribute__((ext_vector_type(4)));
typedef unsigned long long u64;

// gelu tanh-approx in sigmoid form: x*sigmoid(2y), y=a(x+b x^3)
__device__ __forceinline__ float gelu_tanh(float x) {
  float s = x*x;
  float u = __fmaf_rn(-0.0713548194f, s, -1.5957691216f);   // -2ab*s - 2a
  float p = __expf(x*u);
  return x * __builtin_amdgcn_rcpf(1.0f + p);
}

__device__ __forceinline__ int mbcnt64(u64 m) {
  return __builtin_amdgcn_mbcnt_hi((unsigned)(m >> 32),
         __builtin_amdgcn_mbcnt_lo((unsigned)m, 0));
}

// ---------------- kNN v6 (FROZEN: f32 scan chain + ballot bit-descend) --------------
__global__ __launch_bounds__(256) void knn_kernel(const float* __restrict__ pos,
    int* __restrict__ srci, float* __restrict__ dedge) {
  __shared__ u64 sel[4][16];            // per-wave survivor slots (512 B)
  int tid = threadIdx.x;
  int wv = tid >> 6;
  int node = blockIdx.x*4 + wv;
  int lane = tid & 63;
  int base = node & ~(GG-1);
  float qx = pos[(size_t)node*3+0], qy = pos[(size_t)node*3+1], qz = pos[(size_t)node*3+2];

  float d2s[32];
  float c0 = 3.4e38f, c1 = 3.4e38f, c2 = 3.4e38f, c3 = 3.4e38f;
  #pragma unroll
  for (int it = 0; it < 32; ++it) {
    int j = it*64 + lane;
    const float* pr = pos + (size_t)(base+j)*3;
    float dx = __fsub_rn(qx, pr[0]);
    float dy = __fsub_rn(qy, pr[1]);
    float dz = __fsub_rn(qz, pr[2]);
    float d2 = __fadd_rn(__fadd_rn(__fmul_rn(dx,dx), __fmul_rn(dy,dy)), __fmul_rn(dz,dz));
    d2s[it] = d2;
    float x = d2;
    float t0 = fminf(c0, x); x = fmaxf(c0, x); c0 = t0;
    float t1 = fminf(c1, x); x = fmaxf(c1, x); c1 = t1;
    float t2 = fminf(c2, x); x = fmaxf(c2, x); c2 = t2;
    c3 = fminf(c3, x);
  }
  unsigned T = 0;
  for (int b = 30; b >= 0; --b) {
    unsigned tb = T | (1u << b);
    float tf = __uint_as_float(tb);
    int cnt = __popcll(__ballot(c0 < tf)) + __popcll(__ballot(c1 < tf))
            + __popcll(__ballot(c2 < tf)) + __popcll(__ballot(c3 < tf));
    if (cnt < 16) T = tb;
  }
  float Tf = __uint_as_float(T);
  int cless;
  if (!__any(c3 <= Tf)) {
    cless = __popcll(__ballot(c0 < Tf)) + __popcll(__ballot(c1 < Tf))
          + __popcll(__ballot(c2 < Tf)) + __popcll(__ballot(c3 < Tf));
  } else {
    T = 0;
    for (int b = 30; b >= 0; --b) {
      unsigned tb = T | (1u << b);
      float tf = __uint_as_float(tb);
      int cnt = 0;
      #pragma unroll
      for (int q = 0; q < 32; ++q) cnt += __popcll(__ballot(d2s[q] < tf));
      if (cnt < 16) T = tb;
    }
    Tf = __uint_as_float(T);
    cless = 0;
    #pragma unroll
    for (int q = 0; q < 32; ++q) cless += __popcll(__ballot(d2s[q] < Tf));
  }
  int offb = 0;
  int tieq = 16 - cless;
  #pragma unroll
  for (int it = 0; it < 32; ++it) {
    u64 mless = __ballot(d2s[it] < Tf);
    u64 mtie  = __ballot(d2s[it] == Tf);
    bool store = (d2s[it] < Tf);
    int slot = offb + mbcnt64(mless);
    offb += (int)__popcll(mless);
    if (mtie != 0 && tieq > 0) {
      int tr = mbcnt64(mtie);
      if (d2s[it] == Tf && tr < tieq) { store = true; slot = offb + tr; }
      int take = (int)__popcll(mtie); take = take < tieq ? take : tieq;
      offb += take; tieq -= take;
    }
    if (store)
      sel[wv][slot] = ((u64)__float_as_uint(d2s[it]) << 32) | (unsigned)(it*64 + lane);
  }
  if (lane < KNN) {
    u64 e = sel[wv][lane];
    int rank = 0;
    #pragma unroll
    for (int k2 = 0; k2 < 16; ++k2) rank += (sel[wv][k2] < e) ? 1 : 0;
    int j = (int)(e & 0xffffffffu);
    float d2v = __uint_as_float((unsigned)(e >> 32));
    srci[node*KNN + rank] = base + j;
    dedge[node*KNN + rank] = sqrtf(__fadd_rn(d2v, 1e-12f));
  }
}

// ---------------- weight transpose + f16 convert (transposed [col][k] layouts) -------
__global__ __launch_bounds__(256) void prep_kernel(
    const float* __restrict__ Wb2, const float* __restrict__ Wk,
    const float* __restrict__ W1, const float* __restrict__ W2,
    f16* __restrict__ Wb2t, f16* __restrict__ Wkt,
    f16* __restrict__ W1t, f16* __restrict__ W2t) {
  int i = blockIdx.x*256 + threadIdx.x;
  if (i < 16384) {
    int c = i >> 7, k = i & 127;
    Wb2t[i] = (f16)Wb2[k*128 + c];
    return;
  }
  i -= 16384;
  if (i < 65536) {
    int l = i >> 14, r = i & 16383; int c = r >> 7, k = r & 127;
    Wkt[i] = (f16)Wk[l*16384 + k*128 + c];
    return;
  }
  i -= 65536;
  if (i < 262144) {
    int l = i >> 16, r = i & 65535; int c = r >> 7, k = r & 127;   // c<512,k<128
    W1t[i] = (f16)W1[l*65536 + k*512 + c];
    return;
  }
  i -= 262144;
  if (i < 262144) {
    int l = i >> 16, r = i & 65535; int c = r >> 9, k = r & 511;   // c<128,k<512
    W2t[i] = (f16)W2[l*65536 + k*128 + c];
  }
}

// ---------------- embed: h = x[N,65] @ We[65,128] (f32 VALU) -------------------------
__global__ __launch_bounds__(256) void embed_kernel(const float* __restrict__ x,
    const float* __restrict__ We, float* __restrict__ h) {
  int t = threadIdx.x;
  int n = blockIdx.x*8 + (t >> 5);
  int q = (t & 31) * 4;
  f32x4 acc = {0.f,0.f,0.f,0.f};
  const float* xr = x + n*65;
  for (int k = 0; k < 65; ++k) {
    float xv = xr[k];
    f32x4 wv = *(const f32x4*)(We + k*128 + q);
    acc += xv * wv;
  }
  *(f32x4*)(h + (size_t)n*128 + q) = acc;
}

// ---------------- edge basis v5: Wb2 staged in LDS -----------------------------------
__global__ __launch_bounds__(256) void basis_kernel(const float* __restrict__ dedge,
    const float* __restrict__ Wb1, const float* __restrict__ bb1,
    const f16* __restrict__ Wb2t, const float* __restrict__ bb2,
    f16* __restrict__ kernA) {
  __shared__ f16 Wb2s[128][136];  // 34.8KB, padded: B-frag ds_read_b128 2-way max
  __shared__ f16 kb[64][136];     // 17.4KB, rows w*16.. private per wave
  int t = threadIdx.x;
  #pragma unroll
  for (int it = 0; it < 8; ++it) {      // stage Wb2t (32KB) coalesced
    int idx = it*256 + t;
    int row = idx >> 4, k8 = (idx & 15) * 8;
    *(half8*)&Wb2s[row][k8] = *(const half8*)&Wb2t[row*128 + k8];
  }
  __syncthreads();
  int w = t >> 6, l = t & 63;
  int row4 = l >> 4, rlo = l & 15;
  #pragma unroll
  for (int tt = 0; tt < 2; ++tt) {
    size_t Tg = (size_t)blockIdx.x*8 + (size_t)w*2 + tt;
    float d = dedge[Tg*16 + rlo];
    float d2 = d*d, d3 = d2*d;
    half8 a[4];
    #pragma unroll
    for (int kc = 0; kc < 4; ++kc) {
      int k0 = kc*32 + row4*8;
      f32x4 w1a = *(const f32x4*)&Wb1[k0],     w1b = *(const f32x4*)&Wb1[k0+4];
      f32x4 w2a = *(const f32x4*)&Wb1[128+k0], w2b = *(const f32x4*)&Wb1[128+k0+4];
      f32x4 w3a = *(const f32x4*)&Wb1[256+k0], w3b = *(const f32x4*)&Wb1[256+k0+4];
      f32x4 bba = *(const f32x4*)&bb1[k0],     bbb = *(const f32x4*)&bb1[k0+4];
      #pragma unroll
      for (int j = 0; j < 4; ++j) {
        a[kc][j]   = (f16)gelu_tanh(d*w1a[j] + d2*w2a[j] + d3*w3a[j] + bba[j]);
        a[kc][4+j] = (f16)gelu_tanh(d*w1b[j] + d2*w2b[j] + d3*w3b[j] + bbb[j]);
      }
    }
    f32x4 acc[8];
    #pragma unroll
    for (int nt = 0; nt < 8; ++nt) {
      acc[nt] = (f32x4){0.f,0.f,0.f,0.f};
      #pragma unroll
      for (int kc = 0; kc < 4; ++kc) {
        half8 b = *(const half8*)&Wb2s[nt*16 + rlo][kc*32 + row4*8];
        acc[nt] = __builtin_amdgcn_mfma_f32_16x16x32_f16(a[kc], b, acc[nt], 0, 0, 0);
      }
    }
    #pragma unroll
    for (int nt = 0; nt < 8; ++nt) {
      float bias = bb2[nt*16 + rlo];
      #pragma unroll
      for (int j = 0; j < 4; ++j)
        kb[w*16 + row4*4 + j][nt*16 + rlo] = (f16)gelu_tanh(acc[nt][j] + bias);
    }
    #pragma unroll
    for (int kc = 0; kc < 4; ++kc) {
      half8 v = *(const half8*)&kb[w*16 + rlo][kc*32 + row4*8];
      *(half8*)&kernA[((Tg*4 + kc)*64 + l)*8] = v;
    }
  }
}

// ---------------- fused layer v6: R11-v4 structure VERBATIM + XCD swizzle only ------
// R13 lesson: launch_bounds(256,4) + 32 extra VGPRs of hv prefetch -> VGPR capped
// at 64, massive scratch spill (WRITE_SIZE 8->122MB). Reverted. This round's single
// variable: bijective XCD swizzle (zero VGPR cost) for graph-per-XCD L2 locality.
#define LOADA(arr, mm) { \
  int node_ = n0 + w*4 + (mm); \
  _Pragma("unroll") \
  for (int kc = 0; kc < 4; ++kc) \
    arr[kc] = *(const half8*)&kernA[(((size_t)node_*4 + kc)*64 + l)*8]; }

#define COMPM(arr, mm) { \
  float hv[4][4]; \
  _Pragma("unroll") \
  for (int nt4 = 0; nt4 < 4; ++nt4) \
    _Pragma("unroll") \
    for (int j = 0; j < 4; ++j) \
      hv[nt4][j] = hin[(size_t)sidxA[mm][j]*128 + (hh*4 + nt4)*16 + rlo]; \
  _Pragma("unroll") \
  for (int nt4 = 0; nt4 < 4; ++nt4) { \
    f32x4 acc = {0.f,0.f,0.f,0.f}; \
    _Pragma("unroll") \
    for (int kc = 0; kc < 4; ++kc) \
      acc = __builtin_amdgcn_mfma_f32_16x16x32_f16(arr[kc], bf[nt4][kc], acc, 0, 0, 0); \
    float p = 0.f; \
    _Pragma("unroll") \
    for (int j = 0; j < 4; ++j) p += acc[j] * hv[nt4][j]; \
    p += __shfl_xor(p, 16, 64); \
    p += __shfl_xor(p, 32, 64); \
    if (l < 16) aggl[w*4 + (mm)][(hh*4 + nt4)*16 + l] = p; \
  } }

__global__ __launch_bounds__(256) void layer_kernel(const f16* __restrict__ kernA,
    const f16* __restrict__ Wkt_l, const int* __restrict__ srci,
    const float* __restrict__ hin,
    const float* __restrict__ lng, const float* __restrict__ lnb,
    const f16* __restrict__ W1t_l, const float* __restrict__ b1_l,
    const f16* __restrict__ W2t_l, const float* __restrict__ b2_l,
    float* __restrict__ hout) {
  __shared__ float aggl[16][132];   // 8.4KB  conv output (wave-private rows)
  __shared__ f16 zl[16][136];       // 4.4KB  LN output
  __shared__ f16 y1[16][520];       // 16.6KB full y1
  int t = threadIdx.x;
  int w = t >> 6, l = t & 63;
  int row4 = l >> 4, rlo = l & 15;
  // XCD swizzle: physical block i runs on XCD i%8; logical = (i%8)*128 + i/8 puts
  // each graph (128 consecutive logical blocks) wholly on one XCD. Bijective: 1024.
  int bid = (blockIdx.x & 7)*128 + (blockIdx.x >> 3);
  int n0 = bid * 16;

  int sidxA[4][4];
  #pragma unroll
  for (int m = 0; m < 4; ++m)
    #pragma unroll
    for (int j = 0; j < 4; ++j)
      sidxA[m][j] = srci[(n0 + w*4 + m)*16 + row4*4 + j];

  #pragma unroll
  for (int hh = 0; hh < 2; ++hh) {
    half8 bf[4][4];
    #pragma unroll
    for (int nt4 = 0; nt4 < 4; ++nt4)
      #pragma unroll
      for (int kc = 0; kc < 4; ++kc)
        bf[nt4][kc] = *(const half8*)&Wkt_l[((hh*4 + nt4)*16 + rlo)*128 + kc*32 + row4*8];
    half8 aA[4], aB[4];
    LOADA(aA, 0)
    LOADA(aB, 1)
    COMPM(aA, 0)
    LOADA(aA, 2)
    COMPM(aB, 1)
    LOADA(aB, 3)
    COMPM(aA, 2)
    COMPM(aB, 3)
  }
  __syncthreads();
  {
    int row = w*4 + row4;
    int cb = rlo*8;
    f32x4 va = *(const f32x4*)&aggl[row][cb];
    f32x4 vb = *(const f32x4*)&aggl[row][cb+4];
    float s = va[0]+va[1]+va[2]+va[3] + vb[0]+vb[1]+vb[2]+vb[3];
    #pragma unroll
    for (int st = 1; st < 16; st <<= 1) s += __shfl_xor(s, st, 64);
    float mu = s * (1.f/128.f);
    f32x4 da = va - mu, db = vb - mu;
    float s2 = da[0]*da[0]+da[1]*da[1]+da[2]*da[2]+da[3]*da[3]
             + db[0]*db[0]+db[1]*db[1]+db[2]*db[2]+db[3]*db[3];
    #pragma unroll
    for (int st = 1; st < 16; st <<= 1) s2 += __shfl_xor(s2, st, 64);
    float inv = rsqrtf(s2*(1.f/128.f) + 1e-5f);
    f32x4 ga = *(const f32x4*)&lng[cb], gb = *(const f32x4*)&lng[cb+4];
    f32x4 ba = *(const f32x4*)&lnb[cb], bb = *(const f32x4*)&lnb[cb+4];
    f32x4 za = da*inv*ga + ba, zb = db*inv*gb + bb;
    half8 hz = { (f16)za[0],(f16)za[1],(f16)za[2],(f16)za[3],
                 (f16)zb[0],(f16)zb[1],(f16)zb[2],(f16)zb[3] };
    *(half8*)&zl[row][cb] = hz;
  }
  __syncthreads();
  half8 az[4];
  #pragma unroll
  for (int kc = 0; kc < 4; ++kc)
    az[kc] = *(const half8*)&zl[rlo][kc*32 + row4*8];
  #pragma unroll
  for (int ntl = 0; ntl < 8; ++ntl) {
    int nt = w*8 + ntl;
    int col = nt*16 + rlo;
    f32x4 acc = {0.f,0.f,0.f,0.f};
    #pragma unroll
    for (int kc = 0; kc < 4; ++kc) {
      half8 b = *(const half8*)&W1t_l[(size_t)col*128 + kc*32 + row4*8];
      acc = __builtin_amdgcn_mfma_f32_16x16x32_f16(az[kc], b, acc, 0, 0, 0);
    }
    float bias = b1_l[col];
    #pragma unroll
    for (int j = 0; j < 4; ++j)
      y1[row4*4 + j][col] = (f16)gelu_tanh(acc[j] + bias);
  }
  __syncthreads();
  half8 a2[16];
  #pragma unroll
  for (int kc2 = 0; kc2 < 16; ++kc2)
    a2[kc2] = *(const half8*)&y1[rlo][kc2*32 + row4*8];
  f32x4 acc2[2] = {{0.f,0.f,0.f,0.f},{0.f,0.f,0.f,0.f}};
  #pragma unroll
  for (int nt2 = 0; nt2 < 2; ++nt2) {
    int c = (w*2 + nt2)*16 + rlo;
    #pragma unroll
    for (int kc2 = 0; kc2 < 16; ++kc2) {
      half8 b = *(const half8*)&W2t_l[(size_t)c*512 + kc2*32 + row4*8];
      acc2[nt2] = __builtin_amdgcn_mfma_f32_16x16x32_f16(a2[kc2], b, acc2[nt2], 0, 0, 0);
    }
  }
  #pragma unroll
  for (int nt2 = 0; nt2 < 2; ++nt2) {
    int col = (w*2 + nt2)*16 + rlo;
    float bias = b2_l[col];
    #pragma unroll
    for (int j = 0; j < 4; ++j) {
      size_t n = (size_t)(n0 + row4*4 + j);
      hout[n*128 + col] = acc2[nt2][j] + bias + hin[n*128 + col];
    }
  }
}

// ---------------- readout ------------------------------------------------------------
__global__ __launch_bounds__(256) void readout_kernel(const float* __restrict__ h,
    const float* __restrict__ Wr, const float* __restrict__ br, float* __restrict__ out) {
  int n = blockIdx.x*256 + threadIdx.x;
  f32x4 acc = {0.f,0.f,0.f,0.f};
  #pragma unroll
  for (int cb = 0; cb < 32; ++cb) {
    f32x4 hv = *(const f32x4*)(h + (size_t)n*128 + cb*4);
    f32x4 wv = *(const f32x4*)(Wr + cb*4);
    acc += hv*wv;
  }
  out[n] = acc[0]+acc[1]+acc[2]+acc[3] + br[0];
}

extern "C" void kernel_launch(void* const* d_in, const int* in_sizes, int n_in,
                              void* d_out, int out_size, void* d_ws, size_t ws_size,
                              hipStream_t stream) {
  const float* x   = (const float*)d_in[0];
  const float* pos = (const float*)d_in[1];
  const float* We  = (const float*)d_in[3];
  const float* Wb1 = (const float*)d_in[4];
  const float* bb1 = (const float*)d_in[5];
  const float* Wb2 = (const float*)d_in[6];
  const float* bb2 = (const float*)d_in[7];
  const float* Wk  = (const float*)d_in[8];
  const float* lng = (const float*)d_in[9];
  const float* lnb = (const float*)d_in[10];
  const float* W1  = (const float*)d_in[11];
  const float* b1  = (const float*)d_in[12];
  const float* W2  = (const float*)d_in[13];
  const float* b2  = (const float*)d_in[14];
  const float* Wr  = (const float*)d_in[15];
  const float* br  = (const float*)d_in[16];
  float* out = (float*)d_out;

  char* p = (char*)d_ws;
  int*   srci  = (int*)p;     p += (size_t)EE*4;
  float* dedge = (float*)p;   p += (size_t)EE*4;
  f16*   kernA = (f16*)p;     p += (size_t)EE*128*2;
  float* hA    = (float*)p;   p += (size_t)NN*128*4;
  float* hB    = (float*)p;   p += (size_t)NN*128*4;
  f16* Wb2t    = (f16*)p;     p += (size_t)16384*2;
  f16* Wkt     = (f16*)p;     p += (size_t)65536*2;
  f16* W1t     = (f16*)p;     p += (size_t)262144*2;
  f16* W2t     = (f16*)p;     p += (size_t)262144*2;

  prep_kernel<<<2368, 256, 0, stream>>>(Wb2, Wk, W1, W2, Wb2t, Wkt, W1t, W2t);
  knn_kernel<<<NN/4, 256, 0, stream>>>(pos, srci, dedge);
  basis_kernel<<<2048, 256, 0, stream>>>(dedge, Wb1, bb1, Wb2t, bb2, kernA);
  embed_kernel<<<NN/8, 256, 0, stream>>>(x, We, hA);
  float* hin = hA;
  for (int lyr = 0; lyr < NL; ++lyr) {
    float* hout = (hin == hA) ? hB : hA;
    layer_kernel<<<NN/16, 256, 0, stream>>>(kernA, Wkt + lyr*16384, srci, hin,
        lng + lyr*128, lnb + lyr*128,
        W1t + (size_t)lyr*65536, b1 + lyr*512, W2t + (size_t)lyr*65536, b2 + lyr*128, hout);
    hin = hout;
  }
  readout_kernel<<<NN/256, 256, 0, stream>>>(hin, Wr, br, out);
}

// Round 15
// 356.054 us; speedup vs baseline: 1.5571x; 1.0048x over previous
//
#include <hip/hip_runtime.h>
#include <hip/hip_bf16.h>

#define NN 16384
#define GG 2048
#define KNN 16
#define EE (NN*KNN)
#define NL 4

typedef _Float16 f16;
typedef _Float16 half8 __attribute__((ext_vector_type(8)));
typedef _Float16 half4 __attribute__((ext_vector_type(4)));
typedef float f32x4 __attribute__((ext_vector_type(4)));
typedef unsigned long long u64;

// gelu tanh-approx in sigmoid form: x*sigmoid(2y), y=a(x+b x^3)
__device__ __forceinline__ float gelu_tanh(float x) {
  float s = x*x;
  float u = __fmaf_rn(-0.0713548194f, s, -1.5957691216f);   // -2ab*s - 2a
  float p = __expf(x*u);
  return x * __builtin_amdgcn_rcpf(1.0f + p);
}

__device__ __forceinline__ int mbcnt64(u64 m) {
  return __builtin_amdgcn_mbcnt_hi((unsigned)(m >> 32),
         __builtin_amdgcn_mbcnt_lo((unsigned)m, 0));
}

// ---------------- pos -> SoA (TA fix: stride-12B loads were 12 lines/instr) ---------
__global__ __launch_bounds__(256) void possoa_kernel(const float* __restrict__ pos,
    float* __restrict__ posx, float* __restrict__ posy, float* __restrict__ posz) {
  int n = blockIdx.x*256 + threadIdx.x;
  posx[n] = pos[(size_t)n*3+0];
  posy[n] = pos[(size_t)n*3+1];
  posz[n] = pos[(size_t)n*3+2];
}

// ---------------- kNN v7: SoA pos reads (4 lines/instr) + f32 chain + bit-descend ---
__global__ __launch_bounds__(256) void knn_kernel(const float* __restrict__ posx,
    const float* __restrict__ posy, const float* __restrict__ posz,
    int* __restrict__ srci, float* __restrict__ dedge) {
  __shared__ u64 sel[4][16];            // per-wave survivor slots (512 B)
  int tid = threadIdx.x;
  int wv = tid >> 6;
  int node = blockIdx.x*4 + wv;
  int lane = tid & 63;
  int base = node & ~(GG-1);
  float qx = posx[node], qy = posy[node], qz = posz[node];

  float d2s[32];
  float c0 = 3.4e38f, c1 = 3.4e38f, c2 = 3.4e38f, c3 = 3.4e38f;
  #pragma unroll
  for (int it = 0; it < 32; ++it) {
    int j = base + it*64 + lane;
    float dx = __fsub_rn(qx, posx[j]);
    float dy = __fsub_rn(qy, posy[j]);
    float dz = __fsub_rn(qz, posz[j]);
    float d2 = __fadd_rn(__fadd_rn(__fmul_rn(dx,dx), __fmul_rn(dy,dy)), __fmul_rn(dz,dz));
    d2s[it] = d2;
    float x = d2;
    float t0 = fminf(c0, x); x = fmaxf(c0, x); c0 = t0;
    float t1 = fminf(c1, x); x = fmaxf(c1, x); c1 = t1;
    float t2 = fminf(c2, x); x = fmaxf(c2, x); c2 = t2;
    c3 = fminf(c3, x);
  }
  unsigned T = 0;
  for (int b = 30; b >= 0; --b) {
    unsigned tb = T | (1u << b);
    float tf = __uint_as_float(tb);
    int cnt = __popcll(__ballot(c0 < tf)) + __popcll(__ballot(c1 < tf))
            + __popcll(__ballot(c2 < tf)) + __popcll(__ballot(c3 < tf));
    if (cnt < 16) T = tb;
  }
  float Tf = __uint_as_float(T);
  int cless;
  if (!__any(c3 <= Tf)) {
    cless = __popcll(__ballot(c0 < Tf)) + __popcll(__ballot(c1 < Tf))
          + __popcll(__ballot(c2 < Tf)) + __popcll(__ballot(c3 < Tf));
  } else {
    T = 0;
    for (int b = 30; b >= 0; --b) {
      unsigned tb = T | (1u << b);
      float tf = __uint_as_float(tb);
      int cnt = 0;
      #pragma unroll
      for (int q = 0; q < 32; ++q) cnt += __popcll(__ballot(d2s[q] < tf));
      if (cnt < 16) T = tb;
    }
    Tf = __uint_as_float(T);
    cless = 0;
    #pragma unroll
    for (int q = 0; q < 32; ++q) cless += __popcll(__ballot(d2s[q] < Tf));
  }
  int offb = 0;
  int tieq = 16 - cless;
  #pragma unroll
  for (int it = 0; it < 32; ++it) {
    u64 mless = __ballot(d2s[it] < Tf);
    u64 mtie  = __ballot(d2s[it] == Tf);
    bool store = (d2s[it] < Tf);
    int slot = offb + mbcnt64(mless);
    offb += (int)__popcll(mless);
    if (mtie != 0 && tieq > 0) {
      int tr = mbcnt64(mtie);
      if (d2s[it] == Tf && tr < tieq) { store = true; slot = offb + tr; }
      int take = (int)__popcll(mtie); take = take < tieq ? take : tieq;
      offb += take; tieq -= take;
    }
    if (store)
      sel[wv][slot] = ((u64)__float_as_uint(d2s[it]) << 32) | (unsigned)(it*64 + lane);
  }
  if (lane < KNN) {
    u64 e = sel[wv][lane];
    int rank = 0;
    #pragma unroll
    for (int k2 = 0; k2 < 16; ++k2) rank += (sel[wv][k2] < e) ? 1 : 0;
    int j = (int)(e & 0xffffffffu);
    float d2v = __uint_as_float((unsigned)(e >> 32));
    srci[node*KNN + rank] = base + j;
    dedge[node*KNN + rank] = sqrtf(__fadd_rn(d2v, 1e-12f));
  }
}

// ---------------- weight transpose + f16 convert (transposed [col][k] layouts) -------
__global__ __launch_bounds__(256) void prep_kernel(
    const float* __restrict__ Wb2, const float* __restrict__ Wk,
    const float* __restrict__ W1, const float* __restrict__ W2,
    f16* __restrict__ Wb2t, f16* __restrict__ Wkt,
    f16* __restrict__ W1t, f16* __restrict__ W2t) {
  int i = blockIdx.x*256 + threadIdx.x;
  if (i < 16384) {
    int c = i >> 7, k = i & 127;
    Wb2t[i] = (f16)Wb2[k*128 + c];
    return;
  }
  i -= 16384;
  if (i < 65536) {
    int l = i >> 14, r = i & 16383; int c = r >> 7, k = r & 127;
    Wkt[i] = (f16)Wk[l*16384 + k*128 + c];
    return;
  }
  i -= 65536;
  if (i < 262144) {
    int l = i >> 16, r = i & 65535; int c = r >> 7, k = r & 127;   // c<512,k<128
    W1t[i] = (f16)W1[l*65536 + k*512 + c];
    return;
  }
  i -= 262144;
  if (i < 262144) {
    int l = i >> 16, r = i & 65535; int c = r >> 9, k = r & 511;   // c<128,k<512
    W2t[i] = (f16)W2[l*65536 + k*128 + c];
  }
}

// ---------------- embed: h = x[N,65] @ We[65,128] (f32 VALU) -------------------------
__global__ __launch_bounds__(256) void embed_kernel(const float* __restrict__ x,
    const float* __restrict__ We, float* __restrict__ h) {
  int t = threadIdx.x;
  int n = blockIdx.x*8 + (t >> 5);
  int q = (t & 31) * 4;
  f32x4 acc = {0.f,0.f,0.f,0.f};
  const float* xr = x + n*65;
  for (int k = 0; k < 65; ++k) {
    float xv = xr[k];
    f32x4 wv = *(const f32x4*)(We + k*128 + q);
    acc += xv * wv;
  }
  *(f32x4*)(h + (size_t)n*128 + q) = acc;
}

// ---------------- edge basis v5: Wb2 staged in LDS -----------------------------------
__global__ __launch_bounds__(256) void basis_kernel(const float* __restrict__ dedge,
    const float* __restrict__ Wb1, const float* __restrict__ bb1,
    const f16* __restrict__ Wb2t, const float* __restrict__ bb2,
    f16* __restrict__ kernA) {
  __shared__ f16 Wb2s[128][136];  // 34.8KB, padded: B-frag ds_read_b128 2-way max
  __shared__ f16 kb[64][136];     // 17.4KB, rows w*16.. private per wave
  int t = threadIdx.x;
  #pragma unroll
  for (int it = 0; it < 8; ++it) {      // stage Wb2t (32KB) coalesced
    int idx = it*256 + t;
    int row = idx >> 4, k8 = (idx & 15) * 8;
    *(half8*)&Wb2s[row][k8] = *(const half8*)&Wb2t[row*128 + k8];
  }
  __syncthreads();
  int w = t >> 6, l = t & 63;
  int row4 = l >> 4, rlo = l & 15;
  #pragma unroll
  for (int tt = 0; tt < 2; ++tt) {
    size_t Tg = (size_t)blockIdx.x*8 + (size_t)w*2 + tt;
    float d = dedge[Tg*16 + rlo];
    float d2 = d*d, d3 = d2*d;
    half8 a[4];
    #pragma unroll
    for (int kc = 0; kc < 4; ++kc) {
      int k0 = kc*32 + row4*8;
      f32x4 w1a = *(const f32x4*)&Wb1[k0],     w1b = *(const f32x4*)&Wb1[k0+4];
      f32x4 w2a = *(const f32x4*)&Wb1[128+k0], w2b = *(const f32x4*)&Wb1[128+k0+4];
      f32x4 w3a = *(const f32x4*)&Wb1[256+k0], w3b = *(const f32x4*)&Wb1[256+k0+4];
      f32x4 bba = *(const f32x4*)&bb1[k0],     bbb = *(const f32x4*)&bb1[k0+4];
      #pragma unroll
      for (int j = 0; j < 4; ++j) {
        a[kc][j]   = (f16)gelu_tanh(d*w1a[j] + d2*w2a[j] + d3*w3a[j] + bba[j]);
        a[kc][4+j] = (f16)gelu_tanh(d*w1b[j] + d2*w2b[j] + d3*w3b[j] + bbb[j]);
      }
    }
    f32x4 acc[8];
    #pragma unroll
    for (int nt = 0; nt < 8; ++nt) {
      acc[nt] = (f32x4){0.f,0.f,0.f,0.f};
      #pragma unroll
      for (int kc = 0; kc < 4; ++kc) {
        half8 b = *(const half8*)&Wb2s[nt*16 + rlo][kc*32 + row4*8];
        acc[nt] = __builtin_amdgcn_mfma_f32_16x16x32_f16(a[kc], b, acc[nt], 0, 0, 0);
      }
    }
    #pragma unroll
    for (int nt = 0; nt < 8; ++nt) {
      float bias = bb2[nt*16 + rlo];
      #pragma unroll
      for (int j = 0; j < 4; ++j)
        kb[w*16 + row4*4 + j][nt*16 + rlo] = (f16)gelu_tanh(acc[nt][j] + bias);
    }
    #pragma unroll
    for (int kc = 0; kc < 4; ++kc) {
      half8 v = *(const half8*)&kb[w*16 + rlo][kc*32 + row4*8];
      *(half8*)&kernA[((Tg*4 + kc)*64 + l)*8] = v;
    }
  }
}

// ---------------- fused layer v4 (R12-exact: 62.5us known-good; swizzle reverted) ---
#define LOADA(arr, mm) { \
  int node_ = n0 + w*4 + (mm); \
  _Pragma("unroll") \
  for (int kc = 0; kc < 4; ++kc) \
    arr[kc] = *(const half8*)&kernA[(((size_t)node_*4 + kc)*64 + l)*8]; }

#define COMPM(arr, mm) { \
  float hv[4][4]; \
  _Pragma("unroll") \
  for (int nt4 = 0; nt4 < 4; ++nt4) \
    _Pragma("unroll") \
    for (int j = 0; j < 4; ++j) \
      hv[nt4][j] = hin[(size_t)sidxA[mm][j]*128 + (hh*4 + nt4)*16 + rlo]; \
  _Pragma("unroll") \
  for (int nt4 = 0; nt4 < 4; ++nt4) { \
    f32x4 acc = {0.f,0.f,0.f,0.f}; \
    _Pragma("unroll") \
    for (int kc = 0; kc < 4; ++kc) \
      acc = __builtin_amdgcn_mfma_f32_16x16x32_f16(arr[kc], bf[nt4][kc], acc, 0, 0, 0); \
    float p = 0.f; \
    _Pragma("unroll") \
    for (int j = 0; j < 4; ++j) p += acc[j] * hv[nt4][j]; \
    p += __shfl_xor(p, 16, 64); \
    p += __shfl_xor(p, 32, 64); \
    if (l < 16) aggl[w*4 + (mm)][(hh*4 + nt4)*16 + l] = p; \
  } }

__global__ __launch_bounds__(256) void layer_kernel(const f16* __restrict__ kernA,
    const f16* __restrict__ Wkt_l, const int* __restrict__ srci,
    const float* __restrict__ hin,
    const float* __restrict__ lng, const float* __restrict__ lnb,
    const f16* __restrict__ W1t_l, const float* __restrict__ b1_l,
    const f16* __restrict__ W2t_l, const float* __restrict__ b2_l,
    float* __restrict__ hout) {
  __shared__ float aggl[16][132];   // 8.4KB  conv output (wave-private rows)
  __shared__ f16 zl[16][136];       // 4.4KB  LN output
  __shared__ f16 y1[16][520];       // 16.6KB full y1
  int t = threadIdx.x;
  int w = t >> 6, l = t & 63;
  int row4 = l >> 4, rlo = l & 15;
  int n0 = blockIdx.x * 16;

  int sidxA[4][4];
  #pragma unroll
  for (int m = 0; m < 4; ++m)
    #pragma unroll
    for (int j = 0; j < 4; ++j)
      sidxA[m][j] = srci[(n0 + w*4 + m)*16 + row4*4 + j];

  #pragma unroll
  for (int hh = 0; hh < 2; ++hh) {
    half8 bf[4][4];
    #pragma unroll
    for (int nt4 = 0; nt4 < 4; ++nt4)
      #pragma unroll
      for (int kc = 0; kc < 4; ++kc)
        bf[nt4][kc] = *(const half8*)&Wkt_l[((hh*4 + nt4)*16 + rlo)*128 + kc*32 + row4*8];
    half8 aA[4], aB[4];
    LOADA(aA, 0)
    LOADA(aB, 1)
    COMPM(aA, 0)
    LOADA(aA, 2)
    COMPM(aB, 1)
    LOADA(aB, 3)
    COMPM(aA, 2)
    COMPM(aB, 3)
  }
  __syncthreads();
  {
    int row = w*4 + row4;
    int cb = rlo*8;
    f32x4 va = *(const f32x4*)&aggl[row][cb];
    f32x4 vb = *(const f32x4*)&aggl[row][cb+4];
    float s = va[0]+va[1]+va[2]+va[3] + vb[0]+vb[1]+vb[2]+vb[3];
    #pragma unroll
    for (int st = 1; st < 16; st <<= 1) s += __shfl_xor(s, st, 64);
    float mu = s * (1.f/128.f);
    f32x4 da = va - mu, db = vb - mu;
    float s2 = da[0]*da[0]+da[1]*da[1]+da[2]*da[2]+da[3]*da[3]
             + db[0]*db[0]+db[1]*db[1]+db[2]*db[2]+db[3]*db[3];
    #pragma unroll
    for (int st = 1; st < 16; st <<= 1) s2 += __shfl_xor(s2, st, 64);
    float inv = rsqrtf(s2*(1.f/128.f) + 1e-5f);
    f32x4 ga = *(const f32x4*)&lng[cb], gb = *(const f32x4*)&lng[cb+4];
    f32x4 ba = *(const f32x4*)&lnb[cb], bb = *(const f32x4*)&lnb[cb+4];
    f32x4 za = da*inv*ga + ba, zb = db*inv*gb + bb;
    half8 hz = { (f16)za[0],(f16)za[1],(f16)za[2],(f16)za[3],
                 (f16)zb[0],(f16)zb[1],(f16)zb[2],(f16)zb[3] };
    *(half8*)&zl[row][cb] = hz;
  }
  __syncthreads();
  half8 az[4];
  #pragma unroll
  for (int kc = 0; kc < 4; ++kc)
    az[kc] = *(const half8*)&zl[rlo][kc*32 + row4*8];
  #pragma unroll
  for (int ntl = 0; ntl < 8; ++ntl) {
    int nt = w*8 + ntl;
    int col = nt*16 + rlo;
    f32x4 acc = {0.f,0.f,0.f,0.f};
    #pragma unroll
    for (int kc = 0; kc < 4; ++kc) {
      half8 b = *(const half8*)&W1t_l[(size_t)col*128 + kc*32 + row4*8];
      acc = __builtin_amdgcn_mfma_f32_16x16x32_f16(az[kc], b, acc, 0, 0, 0);
    }
    float bias = b1_l[col];
    #pragma unroll
    for (int j = 0; j < 4; ++j)
      y1[row4*4 + j][col] = (f16)gelu_tanh(acc[j] + bias);
  }
  __syncthreads();
  half8 a2[16];
  #pragma unroll
  for (int kc2 = 0; kc2 < 16; ++kc2)
    a2[kc2] = *(const half8*)&y1[rlo][kc2*32 + row4*8];
  f32x4 acc2[2] = {{0.f,0.f,0.f,0.f},{0.f,0.f,0.f,0.f}};
  #pragma unroll
  for (int nt2 = 0; nt2 < 2; ++nt2) {
    int c = (w*2 + nt2)*16 + rlo;
    #pragma unroll
    for (int kc2 = 0; kc2 < 16; ++kc2) {
      half8 b = *(const half8*)&W2t_l[(size_t)c*512 + kc2*32 + row4*8];
      acc2[nt2] = __builtin_amdgcn_mfma_f32_16x16x32_f16(a2[kc2], b, acc2[nt2], 0, 0, 0);
    }
  }
  #pragma unroll
  for (int nt2 = 0; nt2 < 2; ++nt2) {
    int col = (w*2 + nt2)*16 + rlo;
    float bias = b2_l[col];
    #pragma unroll
    for (int j = 0; j < 4; ++j) {
      size_t n = (size_t)(n0 + row4*4 + j);
      hout[n*128 + col] = acc2[nt2][j] + bias + hin[n*128 + col];
    }
  }
}

// ---------------- readout ------------------------------------------------------------
__global__ __launch_bounds__(256) void readout_kernel(const float* __restrict__ h,
    const float* __restrict__ Wr, const float* __restrict__ br, float* __restrict__ out) {
  int n = blockIdx.x*256 + threadIdx.x;
  f32x4 acc = {0.f,0.f,0.f,0.f};
  #pragma unroll
  for (int cb = 0; cb < 32; ++cb) {
    f32x4 hv = *(const f32x4*)(h + (size_t)n*128 + cb*4);
    f32x4 wv = *(const f32x4*)(Wr + cb*4);
    acc += hv*wv;
  }
  out[n] = acc[0]+acc[1]+acc[2]+acc[3] + br[0];
}

extern "C" void kernel_launch(void* const* d_in, const int* in_sizes, int n_in,
                              void* d_out, int out_size, void* d_ws, size_t ws_size,
                              hipStream_t stream) {
  const float* x   = (const float*)d_in[0];
  const float* pos = (const float*)d_in[1];
  const float* We  = (const float*)d_in[3];
  const float* Wb1 = (const float*)d_in[4];
  const float* bb1 = (const float*)d_in[5];
  const float* Wb2 = (const float*)d_in[6];
  const float* bb2 = (const float*)d_in[7];
  const float* Wk  = (const float*)d_in[8];
  const float* lng = (const float*)d_in[9];
  const float* lnb = (const float*)d_in[10];
  const float* W1  = (const float*)d_in[11];
  const float* b1  = (const float*)d_in[12];
  const float* W2  = (const float*)d_in[13];
  const float* b2  = (const float*)d_in[14];
  const float* Wr  = (const float*)d_in[15];
  const float* br  = (const float*)d_in[16];
  float* out = (float*)d_out;

  char* p = (char*)d_ws;
  int*   srci  = (int*)p;     p += (size_t)EE*4;
  float* dedge = (float*)p;   p += (size_t)EE*4;
  f16*   kernA = (f16*)p;     p += (size_t)EE*128*2;
  float* hA    = (float*)p;   p += (size_t)NN*128*4;
  float* hB    = (float*)p;   p += (size_t)NN*128*4;
  f16* Wb2t    = (f16*)p;     p += (size_t)16384*2;
  f16* Wkt     = (f16*)p;     p += (size_t)65536*2;
  f16* W1t     = (f16*)p;     p += (size_t)262144*2;
  f16* W2t     = (f16*)p;     p += (size_t)262144*2;
  float* posx  = (float*)p;   p += (size_t)NN*4;
  float* posy  = (float*)p;   p += (size_t)NN*4;
  float* posz  = (float*)p;   p += (size_t)NN*4;

  possoa_kernel<<<NN/256, 256, 0, stream>>>(pos, posx, posy, posz);
  prep_kernel<<<2368, 256, 0, stream>>>(Wb2, Wk, W1, W2, Wb2t, Wkt, W1t, W2t);
  knn_kernel<<<NN/4, 256, 0, stream>>>(posx, posy, posz, srci, dedge);
  basis_kernel<<<2048, 256, 0, stream>>>(dedge, Wb1, bb1, Wb2t, bb2, kernA);
  embed_kernel<<<NN/8, 256, 0, stream>>>(x, We, hA);
  float* hin = hA;
  for (int lyr = 0; lyr < NL; ++lyr) {
    float* hout = (hin == hA) ? hB : hA;
    layer_kernel<<<NN/16, 256, 0, stream>>>(kernA, Wkt + lyr*16384, srci, hin,
        lng + lyr*128, lnb + lyr*128,
        W1t + (size_t)lyr*65536, b1 + lyr*512, W2t + (size_t)lyr*65536, b2 + lyr*128, hout);
    hin = hout;
  }
  readout_kernel<<<NN/256, 256, 0, stream>>>(hin, Wr, br, out);
}

// Round 16
// 321.163 us; speedup vs baseline: 1.7263x; 1.1086x over previous
//
#include <hip/hip_runtime.h>
#include <hip/hip_bf16.h>

#define NN 16384
#define GG 2048
#define KNN 16
#define EE (NN*KNN)
#define NL 4

typedef _Float16 f16;
typedef _Float16 half8 __attribute__((ext_vector_type(8)));
typedef _Float16 half4 __attribute__((ext_vector_type(4)));
typedef float f32x4 __attribute__((ext_vector_type(4)));
typedef unsigned long long u64;

// gelu tanh-approx in sigmoid form: x*sigmoid(2y), y=a(x+b x^3)
__device__ __forceinline__ float gelu_tanh(float x) {
  float s = x*x;
  float u = __fmaf_rn(-0.0713548194f, s, -1.5957691216f);   // -2ab*s - 2a
  float p = __expf(x*u);
  return x * __builtin_amdgcn_rcpf(1.0f + p);
}

__device__ __forceinline__ int mbcnt64(u64 m) {
  return __builtin_amdgcn_mbcnt_hi((unsigned)(m >> 32),
         __builtin_amdgcn_mbcnt_lo((unsigned)m, 0));
}

// ---------------- pos -> SoA ---------------------------------------------------------
__global__ __launch_bounds__(256) void possoa_kernel(const float* __restrict__ pos,
    float* __restrict__ posx, float* __restrict__ posy, float* __restrict__ posz) {
  int n = blockIdx.x*256 + threadIdx.x;
  posx[n] = pos[(size_t)n*3+0];
  posy[n] = pos[(size_t)n*3+1];
  posz[n] = pos[(size_t)n*3+2];
}

// ---------------- kNN v7 (FROZEN) ---------------------------------------------------
__global__ __launch_bounds__(256) void knn_kernel(const float* __restrict__ posx,
    const float* __restrict__ posy, const float* __restrict__ posz,
    int* __restrict__ srci, float* __restrict__ dedge) {
  __shared__ u64 sel[4][16];            // per-wave survivor slots (512 B)
  int tid = threadIdx.x;
  int wv = tid >> 6;
  int node = blockIdx.x*4 + wv;
  int lane = tid & 63;
  int base = node & ~(GG-1);
  float qx = posx[node], qy = posy[node], qz = posz[node];

  float d2s[32];
  float c0 = 3.4e38f, c1 = 3.4e38f, c2 = 3.4e38f, c3 = 3.4e38f;
  #pragma unroll
  for (int it = 0; it < 32; ++it) {
    int j = base + it*64 + lane;
    float dx = __fsub_rn(qx, posx[j]);
    float dy = __fsub_rn(qy, posy[j]);
    float dz = __fsub_rn(qz, posz[j]);
    float d2 = __fadd_rn(__fadd_rn(__fmul_rn(dx,dx), __fmul_rn(dy,dy)), __fmul_rn(dz,dz));
    d2s[it] = d2;
    float x = d2;
    float t0 = fminf(c0, x); x = fmaxf(c0, x); c0 = t0;
    float t1 = fminf(c1, x); x = fmaxf(c1, x); c1 = t1;
    float t2 = fminf(c2, x); x = fmaxf(c2, x); c2 = t2;
    c3 = fminf(c3, x);
  }
  unsigned T = 0;
  for (int b = 30; b >= 0; --b) {
    unsigned tb = T | (1u << b);
    float tf = __uint_as_float(tb);
    int cnt = __popcll(__ballot(c0 < tf)) + __popcll(__ballot(c1 < tf))
            + __popcll(__ballot(c2 < tf)) + __popcll(__ballot(c3 < tf));
    if (cnt < 16) T = tb;
  }
  float Tf = __uint_as_float(T);
  int cless;
  if (!__any(c3 <= Tf)) {
    cless = __popcll(__ballot(c0 < Tf)) + __popcll(__ballot(c1 < Tf))
          + __popcll(__ballot(c2 < Tf)) + __popcll(__ballot(c3 < Tf));
  } else {
    T = 0;
    for (int b = 30; b >= 0; --b) {
      unsigned tb = T | (1u << b);
      float tf = __uint_as_float(tb);
      int cnt = 0;
      #pragma unroll
      for (int q = 0; q < 32; ++q) cnt += __popcll(__ballot(d2s[q] < tf));
      if (cnt < 16) T = tb;
    }
    Tf = __uint_as_float(T);
    cless = 0;
    #pragma unroll
    for (int q = 0; q < 32; ++q) cless += __popcll(__ballot(d2s[q] < Tf));
  }
  int offb = 0;
  int tieq = 16 - cless;
  #pragma unroll
  for (int it = 0; it < 32; ++it) {
    u64 mless = __ballot(d2s[it] < Tf);
    u64 mtie  = __ballot(d2s[it] == Tf);
    bool store = (d2s[it] < Tf);
    int slot = offb + mbcnt64(mless);
    offb += (int)__popcll(mless);
    if (mtie != 0 && tieq > 0) {
      int tr = mbcnt64(mtie);
      if (d2s[it] == Tf && tr < tieq) { store = true; slot = offb + tr; }
      int take = (int)__popcll(mtie); take = take < tieq ? take : tieq;
      offb += take; tieq -= take;
    }
    if (store)
      sel[wv][slot] = ((u64)__float_as_uint(d2s[it]) << 32) | (unsigned)(it*64 + lane);
  }
  if (lane < KNN) {
    u64 e = sel[wv][lane];
    int rank = 0;
    #pragma unroll
    for (int k2 = 0; k2 < 16; ++k2) rank += (sel[wv][k2] < e) ? 1 : 0;
    int j = (int)(e & 0xffffffffu);
    float d2v = __uint_as_float((unsigned)(e >> 32));
    srci[node*KNN + rank] = base + j;
    dedge[node*KNN + rank] = sqrtf(__fadd_rn(d2v, 1e-12f));
  }
}

// ---------------- weight transpose + f16 convert (transposed [col][k] layouts) -------
__global__ __launch_bounds__(256) void prep_kernel(
    const float* __restrict__ Wb2, const float* __restrict__ Wk,
    const float* __restrict__ W1, const float* __restrict__ W2,
    f16* __restrict__ Wb2t, f16* __restrict__ Wkt,
    f16* __restrict__ W1t, f16* __restrict__ W2t) {
  int i = blockIdx.x*256 + threadIdx.x;
  if (i < 16384) {
    int c = i >> 7, k = i & 127;
    Wb2t[i] = (f16)Wb2[k*128 + c];
    return;
  }
  i -= 16384;
  if (i < 65536) {
    int l = i >> 14, r = i & 16383; int c = r >> 7, k = r & 127;
    Wkt[i] = (f16)Wk[l*16384 + k*128 + c];
    return;
  }
  i -= 65536;
  if (i < 262144) {
    int l = i >> 16, r = i & 65535; int c = r >> 7, k = r & 127;   // c<512,k<128
    W1t[i] = (f16)W1[l*65536 + k*512 + c];
    return;
  }
  i -= 262144;
  if (i < 262144) {
    int l = i >> 16, r = i & 65535; int c = r >> 9, k = r & 511;   // c<128,k<512
    W2t[i] = (f16)W2[l*65536 + k*128 + c];
  }
}

// ---------------- embed: h = x[N,65] @ We[65,128] (f32 VALU) -------------------------
__global__ __launch_bounds__(256) void embed_kernel(const float* __restrict__ x,
    const float* __restrict__ We, float* __restrict__ h) {
  int t = threadIdx.x;
  int n = blockIdx.x*8 + (t >> 5);
  int q = (t & 31) * 4;
  f32x4 acc = {0.f,0.f,0.f,0.f};
  const float* xr = x + n*65;
  for (int k = 0; k < 65; ++k) {
    float xv = xr[k];
    f32x4 wv = *(const f32x4*)(We + k*128 + q);
    acc += xv * wv;
  }
  *(f32x4*)(h + (size_t)n*128 + q) = acc;
}

// ---------------- edge basis v5: Wb2 staged in LDS -----------------------------------
__global__ __launch_bounds__(256) void basis_kernel(const float* __restrict__ dedge,
    const float* __restrict__ Wb1, const float* __restrict__ bb1,
    const f16* __restrict__ Wb2t, const float* __restrict__ bb2,
    f16* __restrict__ kernA) {
  __shared__ f16 Wb2s[128][136];  // 34.8KB, padded: B-frag ds_read_b128 2-way max
  __shared__ f16 kb[64][136];     // 17.4KB, rows w*16.. private per wave
  int t = threadIdx.x;
  #pragma unroll
  for (int it = 0; it < 8; ++it) {      // stage Wb2t (32KB) coalesced
    int idx = it*256 + t;
    int row = idx >> 4, k8 = (idx & 15) * 8;
    *(half8*)&Wb2s[row][k8] = *(const half8*)&Wb2t[row*128 + k8];
  }
  __syncthreads();
  int w = t >> 6, l = t & 63;
  int row4 = l >> 4, rlo = l & 15;
  #pragma unroll
  for (int tt = 0; tt < 2; ++tt) {
    size_t Tg = (size_t)blockIdx.x*8 + (size_t)w*2 + tt;
    float d = dedge[Tg*16 + rlo];
    float d2 = d*d, d3 = d2*d;
    half8 a[4];
    #pragma unroll
    for (int kc = 0; kc < 4; ++kc) {
      int k0 = kc*32 + row4*8;
      f32x4 w1a = *(const f32x4*)&Wb1[k0],     w1b = *(const f32x4*)&Wb1[k0+4];
      f32x4 w2a = *(const f32x4*)&Wb1[128+k0], w2b = *(const f32x4*)&Wb1[128+k0+4];
      f32x4 w3a = *(const f32x4*)&Wb1[256+k0], w3b = *(const f32x4*)&Wb1[256+k0+4];
      f32x4 bba = *(const f32x4*)&bb1[k0],     bbb = *(const f32x4*)&bb1[k0+4];
      #pragma unroll
      for (int j = 0; j < 4; ++j) {
        a[kc][j]   = (f16)gelu_tanh(d*w1a[j] + d2*w2a[j] + d3*w3a[j] + bba[j]);
        a[kc][4+j] = (f16)gelu_tanh(d*w1b[j] + d2*w2b[j] + d3*w3b[j] + bbb[j]);
      }
    }
    f32x4 acc[8];
    #pragma unroll
    for (int nt = 0; nt < 8; ++nt) {
      acc[nt] = (f32x4){0.f,0.f,0.f,0.f};
      #pragma unroll
      for (int kc = 0; kc < 4; ++kc) {
        half8 b = *(const half8*)&Wb2s[nt*16 + rlo][kc*32 + row4*8];
        acc[nt] = __builtin_amdgcn_mfma_f32_16x16x32_f16(a[kc], b, acc[nt], 0, 0, 0);
      }
    }
    #pragma unroll
    for (int nt = 0; nt < 8; ++nt) {
      float bias = bb2[nt*16 + rlo];
      #pragma unroll
      for (int j = 0; j < 4; ++j)
        kb[w*16 + row4*4 + j][nt*16 + rlo] = (f16)gelu_tanh(acc[nt][j] + bias);
    }
    #pragma unroll
    for (int kc = 0; kc < 4; ++kc) {
      half8 v = *(const half8*)&kb[w*16 + rlo][kc*32 + row4*8];
      *(half8*)&kernA[((Tg*4 + kc)*64 + l)*8] = v;
    }
  }
}

// ---------------- fused layer v7: 32 nodes / 512 thr / 2 M-tiles --------------------
// R15 diagnosis: W1/W2 issue 1 weight-load per MFMA; waves 75% vmcnt-stalled at 16
// waves/CU. v7: M=32 -> each B-frag feeds 2 MFMAs (1:2); weight L2-stream per node
// halves; conv->LN barrier removed (aggl rows wave-private). LDS 57.5KB -> 2 blk/CU
// x 8 waves = 16 waves/CU (unchanged). Per-output op order identical -> bit-exact.
#define LOADA(arr, mm) { \
  int node_ = n0 + w*4 + (mm); \
  _Pragma("unroll") \
  for (int kc = 0; kc < 4; ++kc) \
    arr[kc] = *(const half8*)&kernA[(((size_t)node_*4 + kc)*64 + l)*8]; }

#define COMPM(arr, mm) { \
  float hv[4][4]; \
  _Pragma("unroll") \
  for (int nt4 = 0; nt4 < 4; ++nt4) \
    _Pragma("unroll") \
    for (int j = 0; j < 4; ++j) \
      hv[nt4][j] = hin[(size_t)sidxA[mm][j]*128 + (hh*4 + nt4)*16 + rlo]; \
  _Pragma("unroll") \
  for (int nt4 = 0; nt4 < 4; ++nt4) { \
    f32x4 acc = {0.f,0.f,0.f,0.f}; \
    _Pragma("unroll") \
    for (int kc = 0; kc < 4; ++kc) \
      acc = __builtin_amdgcn_mfma_f32_16x16x32_f16(arr[kc], bf[nt4][kc], acc, 0, 0, 0); \
    float p = 0.f; \
    _Pragma("unroll") \
    for (int j = 0; j < 4; ++j) p += acc[j] * hv[nt4][j]; \
    p += __shfl_xor(p, 16, 64); \
    p += __shfl_xor(p, 32, 64); \
    if (l < 16) aggl[w*4 + (mm)][(hh*4 + nt4)*16 + l] = p; \
  } }

__global__ __launch_bounds__(512) void layer_kernel(const f16* __restrict__ kernA,
    const f16* __restrict__ Wkt_l, const int* __restrict__ srci,
    const float* __restrict__ hin,
    const float* __restrict__ lng, const float* __restrict__ lnb,
    const f16* __restrict__ W1t_l, const float* __restrict__ b1_l,
    const f16* __restrict__ W2t_l, const float* __restrict__ b2_l,
    float* __restrict__ hout) {
  __shared__ float aggl[32][132];   // 16.9KB conv output (wave-private rows)
  __shared__ f16 zl[32][136];       // 8.7KB  LN output
  __shared__ f16 y1[32][520];       // 33.3KB full y1 (M=32)
  int t = threadIdx.x;              // 0..511
  int w = t >> 6, l = t & 63;       // 8 waves
  int row4 = l >> 4, rlo = l & 15;
  int n0 = blockIdx.x * 32;

  int sidxA[4][4];
  #pragma unroll
  for (int m = 0; m < 4; ++m)
    #pragma unroll
    for (int j = 0; j < 4; ++j)
      sidxA[m][j] = srci[(n0 + w*4 + m)*16 + row4*4 + j];

  // ---- conv (per-wave identical to v4): wave w -> nodes n0+w*4 .. +3
  #pragma unroll
  for (int hh = 0; hh < 2; ++hh) {
    half8 bf[4][4];
    #pragma unroll
    for (int nt4 = 0; nt4 < 4; ++nt4)
      #pragma unroll
      for (int kc = 0; kc < 4; ++kc)
        bf[nt4][kc] = *(const half8*)&Wkt_l[((hh*4 + nt4)*16 + rlo)*128 + kc*32 + row4*8];
    half8 aA[4], aB[4];
    LOADA(aA, 0)
    LOADA(aB, 1)
    COMPM(aA, 0)
    LOADA(aA, 2)
    COMPM(aB, 1)
    LOADA(aB, 3)
    COMPM(aA, 2)
    COMPM(aB, 3)
  }
  // ---- LayerNorm (aggl rows wave-private -> NO barrier; within-wave LDS RAW ok)
  {
    int row = w*4 + row4;
    int cb = rlo*8;
    f32x4 va = *(const f32x4*)&aggl[row][cb];
    f32x4 vb = *(const f32x4*)&aggl[row][cb+4];
    float s = va[0]+va[1]+va[2]+va[3] + vb[0]+vb[1]+vb[2]+vb[3];
    #pragma unroll
    for (int st = 1; st < 16; st <<= 1) s += __shfl_xor(s, st, 64);
    float mu = s * (1.f/128.f);
    f32x4 da = va - mu, db = vb - mu;
    float s2 = da[0]*da[0]+da[1]*da[1]+da[2]*da[2]+da[3]*da[3]
             + db[0]*db[0]+db[1]*db[1]+db[2]*db[2]+db[3]*db[3];
    #pragma unroll
    for (int st = 1; st < 16; st <<= 1) s2 += __shfl_xor(s2, st, 64);
    float inv = rsqrtf(s2*(1.f/128.f) + 1e-5f);
    f32x4 ga = *(const f32x4*)&lng[cb], gb = *(const f32x4*)&lng[cb+4];
    f32x4 ba = *(const f32x4*)&lnb[cb], bb = *(const f32x4*)&lnb[cb+4];
    f32x4 za = da*inv*ga + ba, zb = db*inv*gb + bb;
    half8 hz = { (f16)za[0],(f16)za[1],(f16)za[2],(f16)za[3],
                 (f16)zb[0],(f16)zb[1],(f16)zb[2],(f16)zb[3] };
    *(half8*)&zl[row][cb] = hz;
  }
  __syncthreads();
  // ---- W1: 32 nt over 8 waves = 4 nt/wave; 2 M-tiles share each B-frag (1:2)
  half8 aza[4], azb[4];
  #pragma unroll
  for (int kc = 0; kc < 4; ++kc) {
    aza[kc] = *(const half8*)&zl[rlo][kc*32 + row4*8];
    azb[kc] = *(const half8*)&zl[16 + rlo][kc*32 + row4*8];
  }
  #pragma unroll
  for (int ntl = 0; ntl < 4; ++ntl) {
    int col = (w*4 + ntl)*16 + rlo;
    f32x4 accA = {0.f,0.f,0.f,0.f}, accB = {0.f,0.f,0.f,0.f};
    #pragma unroll
    for (int kc = 0; kc < 4; ++kc) {
      half8 b = *(const half8*)&W1t_l[(size_t)col*128 + kc*32 + row4*8];
      accA = __builtin_amdgcn_mfma_f32_16x16x32_f16(aza[kc], b, accA, 0, 0, 0);
      accB = __builtin_amdgcn_mfma_f32_16x16x32_f16(azb[kc], b, accB, 0, 0, 0);
    }
    float bias = b1_l[col];
    #pragma unroll
    for (int j = 0; j < 4; ++j) {
      y1[row4*4 + j][col]      = (f16)gelu_tanh(accA[j] + bias);
      y1[16 + row4*4 + j][col] = (f16)gelu_tanh(accB[j] + bias);
    }
  }
  __syncthreads();
  // ---- W2: 1 col-tile/wave (8x16=128 cols); K-loop: 1 B-load + 2 ds_read + 2 MFMA
  {
    int col = w*16 + rlo;
    f32x4 accA = {0.f,0.f,0.f,0.f}, accB = {0.f,0.f,0.f,0.f};
    #pragma unroll
    for (int kc2 = 0; kc2 < 16; ++kc2) {
      half8 b   = *(const half8*)&W2t_l[(size_t)col*512 + kc2*32 + row4*8];
      half8 a2a = *(const half8*)&y1[rlo][kc2*32 + row4*8];
      half8 a2b = *(const half8*)&y1[16 + rlo][kc2*32 + row4*8];
      accA = __builtin_amdgcn_mfma_f32_16x16x32_f16(a2a, b, accA, 0, 0, 0);
      accB = __builtin_amdgcn_mfma_f32_16x16x32_f16(a2b, b, accB, 0, 0, 0);
    }
    float bias = b2_l[col];
    #pragma unroll
    for (int j = 0; j < 4; ++j) {
      size_t na = (size_t)(n0 + row4*4 + j);
      size_t nb = (size_t)(n0 + 16 + row4*4 + j);
      hout[na*128 + col] = accA[j] + bias + hin[na*128 + col];
      hout[nb*128 + col] = accB[j] + bias + hin[nb*128 + col];
    }
  }
}

// ---------------- readout ------------------------------------------------------------
__global__ __launch_bounds__(256) void readout_kernel(const float* __restrict__ h,
    const float* __restrict__ Wr, const float* __restrict__ br, float* __restrict__ out) {
  int n = blockIdx.x*256 + threadIdx.x;
  f32x4 acc = {0.f,0.f,0.f,0.f};
  #pragma unroll
  for (int cb = 0; cb < 32; ++cb) {
    f32x4 hv = *(const f32x4*)(h + (size_t)n*128 + cb*4);
    f32x4 wv = *(const f32x4*)(Wr + cb*4);
    acc += hv*wv;
  }
  out[n] = acc[0]+acc[1]+acc[2]+acc[3] + br[0];
}

extern "C" void kernel_launch(void* const* d_in, const int* in_sizes, int n_in,
                              void* d_out, int out_size, void* d_ws, size_t ws_size,
                              hipStream_t stream) {
  const float* x   = (const float*)d_in[0];
  const float* pos = (const float*)d_in[1];
  const float* We  = (const float*)d_in[3];
  const float* Wb1 = (const float*)d_in[4];
  const float* bb1 = (const float*)d_in[5];
  const float* Wb2 = (const float*)d_in[6];
  const float* bb2 = (const float*)d_in[7];
  const float* Wk  = (const float*)d_in[8];
  const float* lng = (const float*)d_in[9];
  const float* lnb = (const float*)d_in[10];
  const float* W1  = (const float*)d_in[11];
  const float* b1  = (const float*)d_in[12];
  const float* W2  = (const float*)d_in[13];
  const float* b2  = (const float*)d_in[14];
  const float* Wr  = (const float*)d_in[15];
  const float* br  = (const float*)d_in[16];
  float* out = (float*)d_out;

  char* p = (char*)d_ws;
  int*   srci  = (int*)p;     p += (size_t)EE*4;
  float* dedge = (float*)p;   p += (size_t)EE*4;
  f16*   kernA = (f16*)p;     p += (size_t)EE*128*2;
  float* hA    = (float*)p;   p += (size_t)NN*128*4;
  float* hB    = (float*)p;   p += (size_t)NN*128*4;
  f16* Wb2t    = (f16*)p;     p += (size_t)16384*2;
  f16* Wkt     = (f16*)p;     p += (size_t)65536*2;
  f16* W1t     = (f16*)p;     p += (size_t)262144*2;
  f16* W2t     = (f16*)p;     p += (size_t)262144*2;
  float* posx  = (float*)p;   p += (size_t)NN*4;
  float* posy  = (float*)p;   p += (size_t)NN*4;
  float* posz  = (float*)p;   p += (size_t)NN*4;

  possoa_kernel<<<NN/256, 256, 0, stream>>>(pos, posx, posy, posz);
  prep_kernel<<<2368, 256, 0, stream>>>(Wb2, Wk, W1, W2, Wb2t, Wkt, W1t, W2t);
  knn_kernel<<<NN/4, 256, 0, stream>>>(posx, posy, posz, srci, dedge);
  basis_kernel<<<2048, 256, 0, stream>>>(dedge, Wb1, bb1, Wb2t, bb2, kernA);
  embed_kernel<<<NN/8, 256, 0, stream>>>(x, We, hA);
  float* hin = hA;
  for (int lyr = 0; lyr < NL; ++lyr) {
    float* hout = (hin == hA) ? hB : hA;
    layer_kernel<<<NN/32, 512, 0, stream>>>(kernA, Wkt + lyr*16384, srci, hin,
        lng + lyr*128, lnb + lyr*128,
        W1t + (size_t)lyr*65536, b1 + lyr*512, W2t + (size_t)lyr*65536, b2 + lyr*128, hout);
    hin = hout;
  }
  readout_kernel<<<NN/256, 256, 0, stream>>>(hin, Wr, br, out);
}

// Round 17
// 284.007 us; speedup vs baseline: 1.9521x; 1.1308x over previous
//
#include <hip/hip_runtime.h>
#include <hip/hip_bf16.h>

#define NN 16384
#define GG 2048
#define KNN 16
#define EE (NN*KNN)
#define NL 4

typedef _Float16 f16;
typedef _Float16 half8 __attribute__((ext_vector_type(8)));
typedef _Float16 half4 __attribute__((ext_vector_type(4)));
typedef float f32x4 __attribute__((ext_vector_type(4)));
typedef unsigned long long u64;

// gelu tanh-approx in sigmoid form: x*sigmoid(2y), y=a(x+b x^3)
__device__ __forceinline__ float gelu_tanh(float x) {
  float s = x*x;
  float u = __fmaf_rn(-0.0713548194f, s, -1.5957691216f);   // -2ab*s - 2a
  float p = __expf(x*u);
  return x * __builtin_amdgcn_rcpf(1.0f + p);
}

__device__ __forceinline__ int mbcnt64(u64 m) {
  return __builtin_amdgcn_mbcnt_hi((unsigned)(m >> 32),
         __builtin_amdgcn_mbcnt_lo((unsigned)m, 0));
}

// ---------------- pos -> SoA ---------------------------------------------------------
__global__ __launch_bounds__(256) void possoa_kernel(const float* __restrict__ pos,
    float* __restrict__ posx, float* __restrict__ posy, float* __restrict__ posz) {
  int n = blockIdx.x*256 + threadIdx.x;
  posx[n] = pos[(size_t)n*3+0];
  posy[n] = pos[(size_t)n*3+1];
  posz[n] = pos[(size_t)n*3+2];
}

// ---------------- kNN v7 (FROZEN) ---------------------------------------------------
__global__ __launch_bounds__(256) void knn_kernel(const float* __restrict__ posx,
    const float* __restrict__ posy, const float* __restrict__ posz,
    int* __restrict__ srci, float* __restrict__ dedge) {
  __shared__ u64 sel[4][16];            // per-wave survivor slots (512 B)
  int tid = threadIdx.x;
  int wv = tid >> 6;
  int node = blockIdx.x*4 + wv;
  int lane = tid & 63;
  int base = node & ~(GG-1);
  float qx = posx[node], qy = posy[node], qz = posz[node];

  float d2s[32];
  float c0 = 3.4e38f, c1 = 3.4e38f, c2 = 3.4e38f, c3 = 3.4e38f;
  #pragma unroll
  for (int it = 0; it < 32; ++it) {
    int j = base + it*64 + lane;
    float dx = __fsub_rn(qx, posx[j]);
    float dy = __fsub_rn(qy, posy[j]);
    float dz = __fsub_rn(qz, posz[j]);
    float d2 = __fadd_rn(__fadd_rn(__fmul_rn(dx,dx), __fmul_rn(dy,dy)), __fmul_rn(dz,dz));
    d2s[it] = d2;
    float x = d2;
    float t0 = fminf(c0, x); x = fmaxf(c0, x); c0 = t0;
    float t1 = fminf(c1, x); x = fmaxf(c1, x); c1 = t1;
    float t2 = fminf(c2, x); x = fmaxf(c2, x); c2 = t2;
    c3 = fminf(c3, x);
  }
  unsigned T = 0;
  for (int b = 30; b >= 0; --b) {
    unsigned tb = T | (1u << b);
    float tf = __uint_as_float(tb);
    int cnt = __popcll(__ballot(c0 < tf)) + __popcll(__ballot(c1 < tf))
            + __popcll(__ballot(c2 < tf)) + __popcll(__ballot(c3 < tf));
    if (cnt < 16) T = tb;
  }
  float Tf = __uint_as_float(T);
  int cless;
  if (!__any(c3 <= Tf)) {
    cless = __popcll(__ballot(c0 < Tf)) + __popcll(__ballot(c1 < Tf))
          + __popcll(__ballot(c2 < Tf)) + __popcll(__ballot(c3 < Tf));
  } else {
    T = 0;
    for (int b = 30; b >= 0; --b) {
      unsigned tb = T | (1u << b);
      float tf = __uint_as_float(tb);
      int cnt = 0;
      #pragma unroll
      for (int q = 0; q < 32; ++q) cnt += __popcll(__ballot(d2s[q] < tf));
      if (cnt < 16) T = tb;
    }
    Tf = __uint_as_float(T);
    cless = 0;
    #pragma unroll
    for (int q = 0; q < 32; ++q) cless += __popcll(__ballot(d2s[q] < Tf));
  }
  int offb = 0;
  int tieq = 16 - cless;
  #pragma unroll
  for (int it = 0; it < 32; ++it) {
    u64 mless = __ballot(d2s[it] < Tf);
    u64 mtie  = __ballot(d2s[it] == Tf);
    bool store = (d2s[it] < Tf);
    int slot = offb + mbcnt64(mless);
    offb += (int)__popcll(mless);
    if (mtie != 0 && tieq > 0) {
      int tr = mbcnt64(mtie);
      if (d2s[it] == Tf && tr < tieq) { store = true; slot = offb + tr; }
      int take = (int)__popcll(mtie); take = take < tieq ? take : tieq;
      offb += take; tieq -= take;
    }
    if (store)
      sel[wv][slot] = ((u64)__float_as_uint(d2s[it]) << 32) | (unsigned)(it*64 + lane);
  }
  if (lane < KNN) {
    u64 e = sel[wv][lane];
    int rank = 0;
    #pragma unroll
    for (int k2 = 0; k2 < 16; ++k2) rank += (sel[wv][k2] < e) ? 1 : 0;
    int j = (int)(e & 0xffffffffu);
    float d2v = __uint_as_float((unsigned)(e >> 32));
    srci[node*KNN + rank] = base + j;
    dedge[node*KNN + rank] = sqrtf(__fadd_rn(d2v, 1e-12f));
  }
}

// ---------------- weight transpose + f16 convert (transposed [col][k] layouts) -------
__global__ __launch_bounds__(256) void prep_kernel(
    const float* __restrict__ Wb2, const float* __restrict__ Wk,
    const float* __restrict__ W1, const float* __restrict__ W2,
    f16* __restrict__ Wb2t, f16* __restrict__ Wkt,
    f16* __restrict__ W1t, f16* __restrict__ W2t) {
  int i = blockIdx.x*256 + threadIdx.x;
  if (i < 16384) {
    int c = i >> 7, k = i & 127;
    Wb2t[i] = (f16)Wb2[k*128 + c];
    return;
  }
  i -= 16384;
  if (i < 65536) {
    int l = i >> 14, r = i & 16383; int c = r >> 7, k = r & 127;
    Wkt[i] = (f16)Wk[l*16384 + k*128 + c];
    return;
  }
  i -= 65536;
  if (i < 262144) {
    int l = i >> 16, r = i & 65535; int c = r >> 7, k = r & 127;   // c<512,k<128
    W1t[i] = (f16)W1[l*65536 + k*512 + c];
    return;
  }
  i -= 262144;
  if (i < 262144) {
    int l = i >> 16, r = i & 65535; int c = r >> 9, k = r & 511;   // c<128,k<512
    W2t[i] = (f16)W2[l*65536 + k*128 + c];
  }
}

// ---------------- embed: h = x[N,65] @ We[65,128] (f32 VALU) -------------------------
__global__ __launch_bounds__(256) void embed_kernel(const float* __restrict__ x,
    const float* __restrict__ We, float* __restrict__ h) {
  int t = threadIdx.x;
  int n = blockIdx.x*8 + (t >> 5);
  int q = (t & 31) * 4;
  f32x4 acc = {0.f,0.f,0.f,0.f};
  const float* xr = x + n*65;
  for (int k = 0; k < 65; ++k) {
    float xv = xr[k];
    f32x4 wv = *(const f32x4*)(We + k*128 + q);
    acc += xv * wv;
  }
  *(f32x4*)(h + (size_t)n*128 + q) = acc;
}

// ---------------- edge basis v5: Wb2 staged in LDS -----------------------------------
__global__ __launch_bounds__(256) void basis_kernel(const float* __restrict__ dedge,
    const float* __restrict__ Wb1, const float* __restrict__ bb1,
    const f16* __restrict__ Wb2t, const float* __restrict__ bb2,
    f16* __restrict__ kernA) {
  __shared__ f16 Wb2s[128][136];  // 34.8KB, padded: B-frag ds_read_b128 2-way max
  __shared__ f16 kb[64][136];     // 17.4KB, rows w*16.. private per wave
  int t = threadIdx.x;
  #pragma unroll
  for (int it = 0; it < 8; ++it) {      // stage Wb2t (32KB) coalesced
    int idx = it*256 + t;
    int row = idx >> 4, k8 = (idx & 15) * 8;
    *(half8*)&Wb2s[row][k8] = *(const half8*)&Wb2t[row*128 + k8];
  }
  __syncthreads();
  int w = t >> 6, l = t & 63;
  int row4 = l >> 4, rlo = l & 15;
  #pragma unroll
  for (int tt = 0; tt < 2; ++tt) {
    size_t Tg = (size_t)blockIdx.x*8 + (size_t)w*2 + tt;
    float d = dedge[Tg*16 + rlo];
    float d2 = d*d, d3 = d2*d;
    half8 a[4];
    #pragma unroll
    for (int kc = 0; kc < 4; ++kc) {
      int k0 = kc*32 + row4*8;
      f32x4 w1a = *(const f32x4*)&Wb1[k0],     w1b = *(const f32x4*)&Wb1[k0+4];
      f32x4 w2a = *(const f32x4*)&Wb1[128+k0], w2b = *(const f32x4*)&Wb1[128+k0+4];
      f32x4 w3a = *(const f32x4*)&Wb1[256+k0], w3b = *(const f32x4*)&Wb1[256+k0+4];
      f32x4 bba = *(const f32x4*)&bb1[k0],     bbb = *(const f32x4*)&bb1[k0+4];
      #pragma unroll
      for (int j = 0; j < 4; ++j) {
        a[kc][j]   = (f16)gelu_tanh(d*w1a[j] + d2*w2a[j] + d3*w3a[j] + bba[j]);
        a[kc][4+j] = (f16)gelu_tanh(d*w1b[j] + d2*w2b[j] + d3*w3b[j] + bbb[j]);
      }
    }
    f32x4 acc[8];
    #pragma unroll
    for (int nt = 0; nt < 8; ++nt) {
      acc[nt] = (f32x4){0.f,0.f,0.f,0.f};
      #pragma unroll
      for (int kc = 0; kc < 4; ++kc) {
        half8 b = *(const half8*)&Wb2s[nt*16 + rlo][kc*32 + row4*8];
        acc[nt] = __builtin_amdgcn_mfma_f32_16x16x32_f16(a[kc], b, acc[nt], 0, 0, 0);
      }
    }
    #pragma unroll
    for (int nt = 0; nt < 8; ++nt) {
      float bias = bb2[nt*16 + rlo];
      #pragma unroll
      for (int j = 0; j < 4; ++j)
        kb[w*16 + row4*4 + j][nt*16 + rlo] = (f16)gelu_tanh(acc[nt][j] + bias);
    }
    #pragma unroll
    for (int kc = 0; kc < 4; ++kc) {
      half8 v = *(const half8*)&kb[w*16 + rlo][kc*32 + row4*8];
      *(half8*)&kernA[((Tg*4 + kc)*64 + l)*8] = v;
    }
  }
}

// ---------------- fused layer v8: Wkt in LDS + single kernA load + batched hv -------
// R16 audit: conv loaded every kernA frag 2x (once per hh) and streamed bf from
// global per wave. v8: Wkt staged once per block in padded LDS (ds_read 2-way max =
// free); conv node-major: kernA 1x (4 loads), all 32 hv batch-issued, weights via
// LDS. Wkts unions with y1 (conv-only vs MLP-only; LN barrier separates) -> LDS
// 60.4KB, still 2 blk/CU. Per-output MFMA/add order identical -> bit-exact.
__global__ __launch_bounds__(512) void layer_kernel(const f16* __restrict__ kernA,
    const f16* __restrict__ Wkt_l, const int* __restrict__ srci,
    const float* __restrict__ hin,
    const float* __restrict__ lng, const float* __restrict__ lnb,
    const f16* __restrict__ W1t_l, const float* __restrict__ b1_l,
    const f16* __restrict__ W2t_l, const float* __restrict__ b2_l,
    float* __restrict__ hout) {
  __shared__ __align__(16) char smem_u[34816];  // union: Wkts[128][136] | y1[32][520]
  f16 (*Wkts)[136] = (f16(*)[136])smem_u;
  f16 (*y1)[520]   = (f16(*)[520])smem_u;
  __shared__ float aggl[32][132];   // 16.9KB conv output (wave-private rows)
  __shared__ f16 zl[32][136];       // 8.7KB  LN output
  int t = threadIdx.x;              // 0..511
  int w = t >> 6, l = t & 63;       // 8 waves
  int row4 = l >> 4, rlo = l & 15;
  int n0 = blockIdx.x * 32;

  // stage Wkt (32KB) coalesced: 2048 half8 chunks over 512 threads
  #pragma unroll
  for (int it = 0; it < 4; ++it) {
    int idx = it*512 + t;
    int row = idx >> 4, k8 = (idx & 15) * 8;
    *(half8*)&Wkts[row][k8] = *(const half8*)&Wkt_l[row*128 + k8];
  }

  int sidxA[4][4];
  #pragma unroll
  for (int m = 0; m < 4; ++m)
    #pragma unroll
    for (int j = 0; j < 4; ++j)
      sidxA[m][j] = srci[(n0 + w*4 + m)*16 + row4*4 + j];
  __syncthreads();

  // ---- conv node-major: kernA once, hv batched, weights from LDS
  #pragma unroll
  for (int m = 0; m < 4; ++m) {
    int node = n0 + w*4 + m;
    half8 a[4];
    #pragma unroll
    for (int kc = 0; kc < 4; ++kc)
      a[kc] = *(const half8*)&kernA[(((size_t)node*4 + kc)*64 + l)*8];
    float hv[8][4];
    #pragma unroll
    for (int nt = 0; nt < 8; ++nt)
      #pragma unroll
      for (int j = 0; j < 4; ++j)
        hv[nt][j] = hin[(size_t)sidxA[m][j]*128 + nt*16 + rlo];
    #pragma unroll
    for (int nt = 0; nt < 8; ++nt) {
      half8 bf4[4];
      #pragma unroll
      for (int kc = 0; kc < 4; ++kc)
        bf4[kc] = *(const half8*)&Wkts[nt*16 + rlo][kc*32 + row4*8];
      f32x4 acc = {0.f,0.f,0.f,0.f};
      #pragma unroll
      for (int kc = 0; kc < 4; ++kc)
        acc = __builtin_amdgcn_mfma_f32_16x16x32_f16(a[kc], bf4[kc], acc, 0, 0, 0);
      float p = 0.f;
      #pragma unroll
      for (int j = 0; j < 4; ++j) p += acc[j] * hv[nt][j];
      p += __shfl_xor(p, 16, 64);
      p += __shfl_xor(p, 32, 64);
      if (l < 16) aggl[w*4 + m][nt*16 + l] = p;
    }
  }
  // ---- LayerNorm (aggl rows wave-private -> no barrier; within-wave LDS RAW ok)
  {
    int row = w*4 + row4;
    int cb = rlo*8;
    f32x4 va = *(const f32x4*)&aggl[row][cb];
    f32x4 vb = *(const f32x4*)&aggl[row][cb+4];
    float s = va[0]+va[1]+va[2]+va[3] + vb[0]+vb[1]+vb[2]+vb[3];
    #pragma unroll
    for (int st = 1; st < 16; st <<= 1) s += __shfl_xor(s, st, 64);
    float mu = s * (1.f/128.f);
    f32x4 da = va - mu, db = vb - mu;
    float s2 = da[0]*da[0]+da[1]*da[1]+da[2]*da[2]+da[3]*da[3]
             + db[0]*db[0]+db[1]*db[1]+db[2]*db[2]+db[3]*db[3];
    #pragma unroll
    for (int st = 1; st < 16; st <<= 1) s2 += __shfl_xor(s2, st, 64);
    float inv = rsqrtf(s2*(1.f/128.f) + 1e-5f);
    f32x4 ga = *(const f32x4*)&lng[cb], gb = *(const f32x4*)&lng[cb+4];
    f32x4 ba = *(const f32x4*)&lnb[cb], bb = *(const f32x4*)&lnb[cb+4];
    f32x4 za = da*inv*ga + ba, zb = db*inv*gb + bb;
    half8 hz = { (f16)za[0],(f16)za[1],(f16)za[2],(f16)za[3],
                 (f16)zb[0],(f16)zb[1],(f16)zb[2],(f16)zb[3] };
    *(half8*)&zl[row][cb] = hz;
  }
  __syncthreads();   // zl ready for all waves; also separates Wkts reads from y1 writes
  // ---- W1: 32 nt over 8 waves = 4 nt/wave; 2 M-tiles share each B-frag (1:2)
  half8 aza[4], azb[4];
  #pragma unroll
  for (int kc = 0; kc < 4; ++kc) {
    aza[kc] = *(const half8*)&zl[rlo][kc*32 + row4*8];
    azb[kc] = *(const half8*)&zl[16 + rlo][kc*32 + row4*8];
  }
  #pragma unroll
  for (int ntl = 0; ntl < 4; ++ntl) {
    int col = (w*4 + ntl)*16 + rlo;
    f32x4 accA = {0.f,0.f,0.f,0.f}, accB = {0.f,0.f,0.f,0.f};
    #pragma unroll
    for (int kc = 0; kc < 4; ++kc) {
      half8 b = *(const half8*)&W1t_l[(size_t)col*128 + kc*32 + row4*8];
      accA = __builtin_amdgcn_mfma_f32_16x16x32_f16(aza[kc], b, accA, 0, 0, 0);
      accB = __builtin_amdgcn_mfma_f32_16x16x32_f16(azb[kc], b, accB, 0, 0, 0);
    }
    float bias = b1_l[col];
    #pragma unroll
    for (int j = 0; j < 4; ++j) {
      y1[row4*4 + j][col]      = (f16)gelu_tanh(accA[j] + bias);
      y1[16 + row4*4 + j][col] = (f16)gelu_tanh(accB[j] + bias);
    }
  }
  __syncthreads();
  // ---- W2: 1 col-tile/wave; K-loop: 1 B-load + 2 ds_read + 2 MFMA
  {
    int col = w*16 + rlo;
    f32x4 accA = {0.f,0.f,0.f,0.f}, accB = {0.f,0.f,0.f,0.f};
    #pragma unroll
    for (int kc2 = 0; kc2 < 16; ++kc2) {
      half8 b   = *(const half8*)&W2t_l[(size_t)col*512 + kc2*32 + row4*8];
      half8 a2a = *(const half8*)&y1[rlo][kc2*32 + row4*8];
      half8 a2b = *(const half8*)&y1[16 + rlo][kc2*32 + row4*8];
      accA = __builtin_amdgcn_mfma_f32_16x16x32_f16(a2a, b, accA, 0, 0, 0);
      accB = __builtin_amdgcn_mfma_f32_16x16x32_f16(a2b, b, accB, 0, 0, 0);
    }
    float bias = b2_l[col];
    #pragma unroll
    for (int j = 0; j < 4; ++j) {
      size_t na = (size_t)(n0 + row4*4 + j);
      size_t nb = (size_t)(n0 + 16 + row4*4 + j);
      hout[na*128 + col] = accA[j] + bias + hin[na*128 + col];
      hout[nb*128 + col] = accB[j] + bias + hin[nb*128 + col];
    }
  }
}

// ---------------- readout ------------------------------------------------------------
__global__ __launch_bounds__(256) void readout_kernel(const float* __restrict__ h,
    const float* __restrict__ Wr, const float* __restrict__ br, float* __restrict__ out) {
  int n = blockIdx.x*256 + threadIdx.x;
  f32x4 acc = {0.f,0.f,0.f,0.f};
  #pragma unroll
  for (int cb = 0; cb < 32; ++cb) {
    f32x4 hv = *(const f32x4*)(h + (size_t)n*128 + cb*4);
    f32x4 wv = *(const f32x4*)(Wr + cb*4);
    acc += hv*wv;
  }
  out[n] = acc[0]+acc[1]+acc[2]+acc[3] + br[0];
}

extern "C" void kernel_launch(void* const* d_in, const int* in_sizes, int n_in,
                              void* d_out, int out_size, void* d_ws, size_t ws_size,
                              hipStream_t stream) {
  const float* x   = (const float*)d_in[0];
  const float* pos = (const float*)d_in[1];
  const float* We  = (const float*)d_in[3];
  const float* Wb1 = (const float*)d_in[4];
  const float* bb1 = (const float*)d_in[5];
  const float* Wb2 = (const float*)d_in[6];
  const float* bb2 = (const float*)d_in[7];
  const float* Wk  = (const float*)d_in[8];
  const float* lng = (const float*)d_in[9];
  const float* lnb = (const float*)d_in[10];
  const float* W1  = (const float*)d_in[11];
  const float* b1  = (const float*)d_in[12];
  const float* W2  = (const float*)d_in[13];
  const float* b2  = (const float*)d_in[14];
  const float* Wr  = (const float*)d_in[15];
  const float* br  = (const float*)d_in[16];
  float* out = (float*)d_out;

  char* p = (char*)d_ws;
  int*   srci  = (int*)p;     p += (size_t)EE*4;
  float* dedge = (float*)p;   p += (size_t)EE*4;
  f16*   kernA = (f16*)p;     p += (size_t)EE*128*2;
  float* hA    = (float*)p;   p += (size_t)NN*128*4;
  float* hB    = (float*)p;   p += (size_t)NN*128*4;
  f16* Wb2t    = (f16*)p;     p += (size_t)16384*2;
  f16* Wkt     = (f16*)p;     p += (size_t)65536*2;
  f16* W1t     = (f16*)p;     p += (size_t)262144*2;
  f16* W2t     = (f16*)p;     p += (size_t)262144*2;
  float* posx  = (float*)p;   p += (size_t)NN*4;
  float* posy  = (float*)p;   p += (size_t)NN*4;
  float* posz  = (float*)p;   p += (size_t)NN*4;

  possoa_kernel<<<NN/256, 256, 0, stream>>>(pos, posx, posy, posz);
  prep_kernel<<<2368, 256, 0, stream>>>(Wb2, Wk, W1, W2, Wb2t, Wkt, W1t, W2t);
  knn_kernel<<<NN/4, 256, 0, stream>>>(posx, posy, posz, srci, dedge);
  basis_kernel<<<2048, 256, 0, stream>>>(dedge, Wb1, bb1, Wb2t, bb2, kernA);
  embed_kernel<<<NN/8, 256, 0, stream>>>(x, We, hA);
  float* hin = hA;
  for (int lyr = 0; lyr < NL; ++lyr) {
    float* hout = (hin == hA) ? hB : hA;
    layer_kernel<<<NN/32, 512, 0, stream>>>(kernA, Wkt + lyr*16384, srci, hin,
        lng + lyr*128, lnb + lyr*128,
        W1t + (size_t)lyr*65536, b1 + lyr*512, W2t + (size_t)lyr*65536, b2 + lyr*128, hout);
    hin = hout;
  }
  readout_kernel<<<NN/256, 256, 0, stream>>>(hin, Wr, br, out);
}